// Round 1
// baseline (815.264 us; speedup 1.0000x reference)
//
#include <hip/hip_runtime.h>
#include <hip/hip_bf16.h>
#include <math.h>

// Problem constants (from reference)
#define B_  64
#define P_  100
#define N_  1000
#define EMB_ 256
#define H_  16
#define D_  16
#define CTX_ 1024
#define L2E 1.44269504088896340736f

// ---------------------------------------------------------------------------
// Generic f32 GEMM: C[M,N] = A[M,K] @ W[K,N] (+bias). Row-major everywhere.
// BM=BN=128, BK=16, 256 threads, 8x8 micro-tile per thread.
// REQUIRES: M % 128 == 0, N % 128 == 0, K % 16 == 0 (true for all our uses).
// ---------------------------------------------------------------------------
#define GBM 128
#define GBN 128
#define GBK 16

__global__ __launch_bounds__(256) void gemm128(
    const float* __restrict__ A, int lda,
    const float* __restrict__ W, int ldw,
    float* __restrict__ C, int ldc,
    int K,
    const float* __restrict__ bias)
{
    __shared__ float As[GBK][GBM + 4];   // [k][m], row stride 132 floats (16B-aligned)
    __shared__ float Bs[GBK][GBN + 4];   // [k][n]

    const int m0 = blockIdx.x * GBM;
    const int n0 = blockIdx.y * GBN;
    const int tid = threadIdx.x;
    const int tx = tid & 15;        // n direction
    const int ty = tid >> 4;        // m direction

    float acc[8][8];
#pragma unroll
    for (int i = 0; i < 8; ++i)
#pragma unroll
        for (int j = 0; j < 8; ++j) acc[i][j] = 0.f;

    for (int k0 = 0; k0 < K; k0 += GBK) {
        // A tile: 128 rows x 16 k  = 512 float4; 2 per thread; store transposed [k][m]
#pragma unroll
        for (int i = 0; i < 2; ++i) {
            int f4 = tid + i * 256;
            int r  = f4 >> 2;            // 0..127
            int c4 = (f4 & 3) << 2;      // 0,4,8,12
            float4 av = *(const float4*)&A[(size_t)(m0 + r) * lda + k0 + c4];
            As[c4 + 0][r] = av.x;
            As[c4 + 1][r] = av.y;
            As[c4 + 2][r] = av.z;
            As[c4 + 3][r] = av.w;
        }
        // B tile: 16 k x 128 n = 512 float4; natural layout
#pragma unroll
        for (int i = 0; i < 2; ++i) {
            int f4 = tid + i * 256;
            int kk = f4 >> 5;            // 0..15
            int c4 = (f4 & 31) << 2;     // 0..124
            *(float4*)&Bs[kk][c4] = *(const float4*)&W[(size_t)(k0 + kk) * ldw + n0 + c4];
        }
        __syncthreads();

#pragma unroll
        for (int kk = 0; kk < GBK; ++kk) {
            float a[8], b[8];
            float4 t;
            t = *(const float4*)&As[kk][ty * 4];      a[0]=t.x; a[1]=t.y; a[2]=t.z; a[3]=t.w;
            t = *(const float4*)&As[kk][64 + ty * 4]; a[4]=t.x; a[5]=t.y; a[6]=t.z; a[7]=t.w;
            t = *(const float4*)&Bs[kk][tx * 4];      b[0]=t.x; b[1]=t.y; b[2]=t.z; b[3]=t.w;
            t = *(const float4*)&Bs[kk][64 + tx * 4]; b[4]=t.x; b[5]=t.y; b[6]=t.z; b[7]=t.w;
#pragma unroll
            for (int i = 0; i < 8; ++i)
#pragma unroll
                for (int j = 0; j < 8; ++j)
                    acc[i][j] = fmaf(a[i], b[j], acc[i][j]);
        }
        __syncthreads();
    }

    // Epilogue
#pragma unroll
    for (int i = 0; i < 8; ++i) {
        int r = (i < 4) ? (ty * 4 + i) : (64 + ty * 4 + (i - 4));
        size_t base = (size_t)(m0 + r) * ldc + n0;
#pragma unroll
        for (int jh = 0; jh < 2; ++jh) {
            int c = jh * 64 + tx * 4;
            float4 o;
            o.x = acc[i][jh * 4 + 0];
            o.y = acc[i][jh * 4 + 1];
            o.z = acc[i][jh * 4 + 2];
            o.w = acc[i][jh * 4 + 3];
            if (bias) {
                o.x += bias[n0 + c + 0];
                o.y += bias[n0 + c + 1];
                o.z += bias[n0 + c + 2];
                o.w += bias[n0 + c + 3];
            }
            *(float4*)&C[base + c] = o;
        }
    }
}

// ---------------------------------------------------------------------------
// qc[b][n] = sum_k ctx[b][k] * Wq[260 + k][n]   (per-batch context projection)
// ---------------------------------------------------------------------------
__global__ __launch_bounds__(256) void qc_kernel(
    const float* __restrict__ ctx, const float* __restrict__ Wq,
    float* __restrict__ qc)
{
    __shared__ float cs[CTX_];
    const int b = blockIdx.x;
    const int tid = threadIdx.x;
#pragma unroll
    for (int i = 0; i < 4; ++i) cs[tid + i * 256] = ctx[(size_t)b * CTX_ + tid + i * 256];
    __syncthreads();
    float acc = 0.f;
    const float* w = Wq + (size_t)260 * EMB_ + tid;  // column tid, rows 260..1283
#pragma unroll 8
    for (int kk = 0; kk < CTX_; ++kk)
        acc = fmaf(cs[kk], w[(size_t)kk * EMB_], acc);
    qc[(size_t)b * EMB_ + tid] = acc;
}

// ---------------------------------------------------------------------------
// q[m][n] += attr[m][0..3] . Wq[256..259][n]  +  qc[b][n]
// ---------------------------------------------------------------------------
__global__ __launch_bounds__(256) void qfix_kernel(
    const float* __restrict__ attr, const float* __restrict__ Wq,
    const float* __restrict__ qc, float* __restrict__ q)
{
    const int idx = blockIdx.x * 256 + threadIdx.x;   // 6400*256 total
    const int n = idx & 255;
    const int m = idx >> 8;      // 0..6399
    const int b = m / P_;
    float a0 = attr[(size_t)m * 4 + 0];
    float a1 = attr[(size_t)m * 4 + 1];
    float a2 = attr[(size_t)m * 4 + 2];
    float a3 = attr[(size_t)m * 4 + 3];
    float add = qc[(size_t)b * EMB_ + n];
    add = fmaf(a0, Wq[(size_t)256 * EMB_ + n], add);
    add = fmaf(a1, Wq[(size_t)257 * EMB_ + n], add);
    add = fmaf(a2, Wq[(size_t)258 * EMB_ + n], add);
    add = fmaf(a3, Wq[(size_t)259 * EMB_ + n], add);
    q[idx] += add;
}

// ---------------------------------------------------------------------------
// Flash attention, f32. One block per (h, b), 128 threads, thread p = tid<100.
// q,k,v layouts: q[(b*P+p)*256 + h*16+d], k/v[(b*N+n)*256 + h*16+d]
// out[(b*P+p)*256 + h*16+d]  (== out_concat layout)
// ---------------------------------------------------------------------------
__global__ __launch_bounds__(128) void attn_kernel(
    const float* __restrict__ q, const float* __restrict__ k,
    const float* __restrict__ v, const float* __restrict__ mask,
    float* __restrict__ out)
{
    __shared__ float ks[64][16];
    __shared__ float vs[64][16];
    const int h = blockIdx.x;
    const int b = blockIdx.y;
    const int tid = threadIdx.x;
    const int p = tid;

    float qreg[16];
    if (p < P_) {
        const float* qp = &q[((size_t)(b * P_ + p)) * 256 + h * 16];
#pragma unroll
        for (int d4 = 0; d4 < 4; ++d4) {
            float4 t = *(const float4*)&qp[d4 * 4];
            qreg[d4 * 4 + 0] = t.x; qreg[d4 * 4 + 1] = t.y;
            qreg[d4 * 4 + 2] = t.z; qreg[d4 * 4 + 3] = t.w;
        }
    }

    float m = -INFINITY, l = 0.f;
    float acc[16];
#pragma unroll
    for (int d = 0; d < 16; ++d) acc[d] = 0.f;

    const float* maskrow = &mask[((size_t)(b * P_ + (p < P_ ? p : 0))) * N_];

    for (int n0 = 0; n0 < N_; n0 += 64) {
        // stage k/v tile (128 threads x 2 float4 each per matrix)
#pragma unroll
        for (int i = 0; i < 2; ++i) {
            int f4 = tid + i * 128;
            int r  = f4 >> 2;
            int c4 = (f4 & 3) << 2;
            int n  = n0 + r; if (n > N_ - 1) n = N_ - 1;
            size_t src = ((size_t)b * N_ + n) * 256 + h * 16 + c4;
            *(float4*)&ks[r][c4] = *(const float4*)&k[src];
            *(float4*)&vs[r][c4] = *(const float4*)&v[src];
        }
        __syncthreads();

        if (p < P_) {
#pragma unroll
            for (int c0 = 0; c0 < 64; c0 += 16) {
                float s[16];
                float tmax = -INFINITY;
#pragma unroll
                for (int i = 0; i < 16; ++i) {
                    int r = c0 + i;
                    int n = n0 + r;
                    float dot = 0.f;
#pragma unroll
                    for (int dq = 0; dq < 4; ++dq) {
                        float4 kk4 = *(const float4*)&ks[r][dq * 4];
                        dot = fmaf(qreg[dq * 4 + 0], kk4.x, dot);
                        dot = fmaf(qreg[dq * 4 + 1], kk4.y, dot);
                        dot = fmaf(qreg[dq * 4 + 2], kk4.z, dot);
                        dot = fmaf(qreg[dq * 4 + 3], kk4.w, dot);
                    }
                    s[i] = (n < N_) ? (dot * 0.25f + maskrow[n]) : -3.0e38f;
                    tmax = fmaxf(tmax, s[i]);
                }
                float mn = fmaxf(m, tmax);
                if (mn > m) {
                    float f = exp2f((m - mn) * L2E);
                    l *= f;
#pragma unroll
                    for (int d = 0; d < 16; ++d) acc[d] *= f;
                    m = mn;
                }
#pragma unroll
                for (int i = 0; i < 16; ++i) {
                    float w = exp2f((s[i] - m) * L2E);
                    l += w;
#pragma unroll
                    for (int dq = 0; dq < 4; ++dq) {
                        float4 vv = *(const float4*)&vs[c0 + i][dq * 4];
                        acc[dq * 4 + 0] = fmaf(w, vv.x, acc[dq * 4 + 0]);
                        acc[dq * 4 + 1] = fmaf(w, vv.y, acc[dq * 4 + 1]);
                        acc[dq * 4 + 2] = fmaf(w, vv.z, acc[dq * 4 + 2]);
                        acc[dq * 4 + 3] = fmaf(w, vv.w, acc[dq * 4 + 3]);
                    }
                }
            }
        }
        __syncthreads();
    }

    if (p < P_) {
        float inv = 1.0f / l;
        float* op = &out[((size_t)(b * P_ + p)) * 256 + h * 16];
#pragma unroll
        for (int d4 = 0; d4 < 4; ++d4) {
            float4 o;
            o.x = acc[d4 * 4 + 0] * inv;
            o.y = acc[d4 * 4 + 1] * inv;
            o.z = acc[d4 * 4 + 2] * inv;
            o.w = acc[d4 * 4 + 3] * inv;
            *(float4*)&op[d4 * 4] = o;
        }
    }
}

// ---------------------------------------------------------------------------
// logits[b,p,n] = 10*tanh( (mh[b,p,:] . nodes[b,n,:]) / 16 ) + mask[b,p,n]
// A@B^T tiling: 64x64 tile, BK=32, 256 threads, 4x4 micro.
// grid = (nb=16, pb=2, b=64)
// ---------------------------------------------------------------------------
#define LBK 32
__global__ __launch_bounds__(256) void logits_kernel(
    const float* __restrict__ mh, const float* __restrict__ nodes,
    const float* __restrict__ mask, float* __restrict__ out)
{
    __shared__ float As[LBK][68];   // [k][p]  row stride 68 floats (16B-aligned)
    __shared__ float Bs[LBK][68];   // [k][n]

    const int nb = blockIdx.x, pb = blockIdx.y, b = blockIdx.z;
    const int p0 = pb * 64, n0 = nb * 64;
    const int tid = threadIdx.x;
    const int tx = tid & 15, ty = tid >> 4;

    const float* Ab = &mh[(size_t)b * P_ * EMB_];
    const float* Bb = &nodes[(size_t)b * N_ * EMB_];

    float acc[4][4];
#pragma unroll
    for (int i = 0; i < 4; ++i)
#pragma unroll
        for (int j = 0; j < 4; ++j) acc[i][j] = 0.f;

    for (int k0 = 0; k0 < EMB_; k0 += LBK) {
        // A tile: 64 rows x 32 k = 512 float4, transposed store
#pragma unroll
        for (int i = 0; i < 2; ++i) {
            int f4 = tid + i * 256;
            int r  = f4 >> 3;            // 0..63
            int c4 = (f4 & 7) << 2;      // 0..28
            int p  = p0 + r;
            float4 av = (p < P_) ? *(const float4*)&Ab[(size_t)p * EMB_ + k0 + c4]
                                 : float4{0.f, 0.f, 0.f, 0.f};
            As[c4 + 0][r] = av.x; As[c4 + 1][r] = av.y;
            As[c4 + 2][r] = av.z; As[c4 + 3][r] = av.w;
        }
        // B tile (nodes rows): 64 rows x 32 k, transposed store
#pragma unroll
        for (int i = 0; i < 2; ++i) {
            int f4 = tid + i * 256;
            int r  = f4 >> 3;
            int c4 = (f4 & 7) << 2;
            int n  = n0 + r; if (n > N_ - 1) n = N_ - 1;
            float4 bv = *(const float4*)&Bb[(size_t)n * EMB_ + k0 + c4];
            Bs[c4 + 0][r] = bv.x; Bs[c4 + 1][r] = bv.y;
            Bs[c4 + 2][r] = bv.z; Bs[c4 + 3][r] = bv.w;
        }
        __syncthreads();

#pragma unroll
        for (int kk = 0; kk < LBK; ++kk) {
            float4 a = *(const float4*)&As[kk][ty * 4];
            float4 bb = *(const float4*)&Bs[kk][tx * 4];
            float av[4] = {a.x, a.y, a.z, a.w};
            float bv[4] = {bb.x, bb.y, bb.z, bb.w};
#pragma unroll
            for (int i = 0; i < 4; ++i)
#pragma unroll
                for (int j = 0; j < 4; ++j)
                    acc[i][j] = fmaf(av[i], bv[j], acc[i][j]);
        }
        __syncthreads();
    }

#pragma unroll
    for (int i = 0; i < 4; ++i) {
        int p = p0 + ty * 4 + i;
        if (p >= P_) continue;
#pragma unroll
        for (int j = 0; j < 4; ++j) {
            int n = n0 + tx * 4 + j;
            if (n >= N_) continue;
            float x = acc[i][j] * (1.0f / 16.0f);
            // tanh(x) = 1 - 2/(exp(2x)+1), exp via exp2
            float e = exp2f(x * (2.0f * L2E));
            float t = 1.0f - 2.0f / (e + 1.0f);
            size_t o = ((size_t)(b * P_ + p)) * N_ + n;
            out[o] = 10.0f * t + mask[o];
        }
    }
}

// ---------------------------------------------------------------------------
// In-place row softmax over N=1000. One block per row (B*P rows), 256 threads.
// ---------------------------------------------------------------------------
__global__ __launch_bounds__(256) void softmax_kernel(float* __restrict__ io)
{
    const size_t row = blockIdx.x;
    float* r = &io[row * N_];
    const int tid = threadIdx.x;
    const int wave = tid >> 6, lane = tid & 63;

    float vals[4];
    float mx = -INFINITY;
#pragma unroll
    for (int j = 0; j < 4; ++j) {
        int n = tid + j * 256;
        vals[j] = (n < N_) ? r[n] : -INFINITY;
        mx = fmaxf(mx, vals[j]);
    }
#pragma unroll
    for (int off = 32; off > 0; off >>= 1) mx = fmaxf(mx, __shfl_down(mx, off));
    __shared__ float redm[4];
    if (lane == 0) redm[wave] = mx;
    __syncthreads();
    mx = fmaxf(fmaxf(redm[0], redm[1]), fmaxf(redm[2], redm[3]));

    float sum = 0.f;
#pragma unroll
    for (int j = 0; j < 4; ++j) {
        float w = exp2f((vals[j] - mx) * L2E);
        vals[j] = w;
        sum += w;
    }
#pragma unroll
    for (int off = 32; off > 0; off >>= 1) sum += __shfl_down(sum, off);
    __shared__ float reds[4];
    if (lane == 0) reds[wave] = sum;
    __syncthreads();
    sum = reds[0] + reds[1] + reds[2] + reds[3];

    float inv = 1.0f / sum;
#pragma unroll
    for (int j = 0; j < 4; ++j) {
        int n = tid + j * 256;
        if (n < N_) r[n] = vals[j] * inv;
    }
}

// ---------------------------------------------------------------------------
extern "C" void kernel_launch(void* const* d_in, const int* in_sizes, int n_in,
                              void* d_out, int out_size, void* d_ws, size_t ws_size,
                              hipStream_t stream)
{
    const float* lastnode = (const float*)d_in[0];   // [B,P,256]
    const float* attr     = (const float*)d_in[1];   // [B,P,4]
    const float* ctx      = (const float*)d_in[2];   // [B,1024]
    const float* mask     = (const float*)d_in[3];   // [B,P,N]
    const float* nodes    = (const float*)d_in[4];   // [B,N,256]
    const float* Wq       = (const float*)d_in[5];   // [1284,256]
    const float* Wk       = (const float*)d_in[6];   // [256,256]
    const float* Wv       = (const float*)d_in[7];   // [256,256]
    const float* Wcomb    = (const float*)d_in[8];   // [256,256]
    const float* bcomb    = (const float*)d_in[9];   // [256]
    float* out = (float*)d_out;

    // Workspace layout (floats). Total 37,699,584 floats = 150.8 MB.
    float* ws    = (float*)d_ws;
    float* kbuf  = ws;                    // 64000*256
    float* vbuf  = kbuf + 16384000;       // 64000*256
    float* qbuf  = vbuf + 16384000;       // 6400*256
    float* abuf  = qbuf + 1638400;        // 6400*256
    float* mhbuf = abuf + 1638400;        // 6400*256
    float* qcbuf = mhbuf + 1638400;       // 64*256

    // k, v projections: M=64000, N=256, K=256
    gemm128<<<dim3(500, 2), 256, 0, stream>>>(nodes, 256, Wk, 256, kbuf, 256, 256, nullptr);
    gemm128<<<dim3(500, 2), 256, 0, stream>>>(nodes, 256, Wv, 256, vbuf, 256, 256, nullptr);

    // q: main term + per-batch ctx projection + attr rank-4 fixup
    qc_kernel<<<64, 256, 0, stream>>>(ctx, Wq, qcbuf);
    gemm128<<<dim3(50, 2), 256, 0, stream>>>(lastnode, 256, Wq, 256, qbuf, 256, 256, nullptr);
    qfix_kernel<<<6400, 256, 0, stream>>>(attr, Wq, qcbuf, qbuf);

    // attention
    attn_kernel<<<dim3(H_, B_), 128, 0, stream>>>(qbuf, kbuf, vbuf, mask, abuf);

    // combine
    gemm128<<<dim3(50, 2), 256, 0, stream>>>(abuf, 256, Wcomb, 256, mhbuf, 256, 256, bcomb);

    // pointer logits into d_out, then in-place softmax
    logits_kernel<<<dim3(16, 2, 64), 256, 0, stream>>>(mhbuf, nodes, mask, out);
    softmax_kernel<<<B_ * P_, 256, 0, stream>>>(out);
}

// Round 2
// 679.127 us; speedup vs baseline: 1.2005x; 1.2005x over previous
//
#include <hip/hip_runtime.h>
#include <hip/hip_bf16.h>
#include <math.h>

// Problem constants (from reference)
#define B_  64
#define P_  100
#define N_  1000
#define EMB_ 256
#define H_  16
#define D_  16
#define CTX_ 1024
#define L2E 1.44269504088896340736f

#if __has_builtin(__builtin_amdgcn_exp2f)
#define EXP2F(x) __builtin_amdgcn_exp2f(x)
#else
#define EXP2F(x) exp2f(x)
#endif

// ---------------------------------------------------------------------------
// Generic f32 GEMM: C[M,N] = A[M,K] @ W[K,N] (+bias). Row-major everywhere.
// BM=BN=128, BK=16, 256 threads, 8x8 micro-tile per thread.
// REQUIRES: M % 128 == 0, N % 128 == 0, K % 16 == 0 (true for all our uses).
// ---------------------------------------------------------------------------
#define GBM 128
#define GBN 128
#define GBK 16

__global__ __launch_bounds__(256) void gemm128(
    const float* __restrict__ A, int lda,
    const float* __restrict__ W, int ldw,
    float* __restrict__ C, int ldc,
    int K,
    const float* __restrict__ bias)
{
    __shared__ float As[GBK][GBM + 4];   // [k][m], row stride 132 floats (16B-aligned)
    __shared__ float Bs[GBK][GBN + 4];   // [k][n]

    const int m0 = blockIdx.x * GBM;
    const int n0 = blockIdx.y * GBN;
    const int tid = threadIdx.x;
    const int tx = tid & 15;        // n direction
    const int ty = tid >> 4;        // m direction

    float acc[8][8];
#pragma unroll
    for (int i = 0; i < 8; ++i)
#pragma unroll
        for (int j = 0; j < 8; ++j) acc[i][j] = 0.f;

    for (int k0 = 0; k0 < K; k0 += GBK) {
        // A tile: 128 rows x 16 k  = 512 float4; 2 per thread; store transposed [k][m]
#pragma unroll
        for (int i = 0; i < 2; ++i) {
            int f4 = tid + i * 256;
            int r  = f4 >> 2;            // 0..127
            int c4 = (f4 & 3) << 2;      // 0,4,8,12
            float4 av = *(const float4*)&A[(size_t)(m0 + r) * lda + k0 + c4];
            As[c4 + 0][r] = av.x;
            As[c4 + 1][r] = av.y;
            As[c4 + 2][r] = av.z;
            As[c4 + 3][r] = av.w;
        }
        // B tile: 16 k x 128 n = 512 float4; natural layout
#pragma unroll
        for (int i = 0; i < 2; ++i) {
            int f4 = tid + i * 256;
            int kk = f4 >> 5;            // 0..15
            int c4 = (f4 & 31) << 2;     // 0..124
            *(float4*)&Bs[kk][c4] = *(const float4*)&W[(size_t)(k0 + kk) * ldw + n0 + c4];
        }
        __syncthreads();

#pragma unroll
        for (int kk = 0; kk < GBK; ++kk) {
            float a[8], b[8];
            float4 t;
            t = *(const float4*)&As[kk][ty * 4];      a[0]=t.x; a[1]=t.y; a[2]=t.z; a[3]=t.w;
            t = *(const float4*)&As[kk][64 + ty * 4]; a[4]=t.x; a[5]=t.y; a[6]=t.z; a[7]=t.w;
            t = *(const float4*)&Bs[kk][tx * 4];      b[0]=t.x; b[1]=t.y; b[2]=t.z; b[3]=t.w;
            t = *(const float4*)&Bs[kk][64 + tx * 4]; b[4]=t.x; b[5]=t.y; b[6]=t.z; b[7]=t.w;
#pragma unroll
            for (int i = 0; i < 8; ++i)
#pragma unroll
                for (int j = 0; j < 8; ++j)
                    acc[i][j] = fmaf(a[i], b[j], acc[i][j]);
        }
        __syncthreads();
    }

    // Epilogue
#pragma unroll
    for (int i = 0; i < 8; ++i) {
        int r = (i < 4) ? (ty * 4 + i) : (64 + ty * 4 + (i - 4));
        size_t base = (size_t)(m0 + r) * ldc + n0;
#pragma unroll
        for (int jh = 0; jh < 2; ++jh) {
            int c = jh * 64 + tx * 4;
            float4 o;
            o.x = acc[i][jh * 4 + 0];
            o.y = acc[i][jh * 4 + 1];
            o.z = acc[i][jh * 4 + 2];
            o.w = acc[i][jh * 4 + 3];
            if (bias) {
                o.x += bias[n0 + c + 0];
                o.y += bias[n0 + c + 1];
                o.z += bias[n0 + c + 2];
                o.w += bias[n0 + c + 3];
            }
            *(float4*)&C[base + c] = o;
        }
    }
}

// ---------------------------------------------------------------------------
// qc[b][n] = sum_k ctx[b][k] * Wq[260 + k][n]   (per-batch context projection)
// ---------------------------------------------------------------------------
__global__ __launch_bounds__(256) void qc_kernel(
    const float* __restrict__ ctx, const float* __restrict__ Wq,
    float* __restrict__ qc)
{
    __shared__ float cs[CTX_];
    const int b = blockIdx.x;
    const int tid = threadIdx.x;
#pragma unroll
    for (int i = 0; i < 4; ++i) cs[tid + i * 256] = ctx[(size_t)b * CTX_ + tid + i * 256];
    __syncthreads();
    float acc = 0.f;
    const float* w = Wq + (size_t)260 * EMB_ + tid;  // column tid, rows 260..1283
#pragma unroll 8
    for (int kk = 0; kk < CTX_; ++kk)
        acc = fmaf(cs[kk], w[(size_t)kk * EMB_], acc);
    qc[(size_t)b * EMB_ + tid] = acc;
}

// ---------------------------------------------------------------------------
// q[m][n] += attr[m][0..3] . Wq[256..259][n]  +  qc[b][n]
// ---------------------------------------------------------------------------
__global__ __launch_bounds__(256) void qfix_kernel(
    const float* __restrict__ attr, const float* __restrict__ Wq,
    const float* __restrict__ qc, float* __restrict__ q)
{
    const int idx = blockIdx.x * 256 + threadIdx.x;   // 6400*256 total
    const int n = idx & 255;
    const int m = idx >> 8;      // 0..6399
    const int b = m / P_;
    float a0 = attr[(size_t)m * 4 + 0];
    float a1 = attr[(size_t)m * 4 + 1];
    float a2 = attr[(size_t)m * 4 + 2];
    float a3 = attr[(size_t)m * 4 + 3];
    float add = qc[(size_t)b * EMB_ + n];
    add = fmaf(a0, Wq[(size_t)256 * EMB_ + n], add);
    add = fmaf(a1, Wq[(size_t)257 * EMB_ + n], add);
    add = fmaf(a2, Wq[(size_t)258 * EMB_ + n], add);
    add = fmaf(a3, Wq[(size_t)259 * EMB_ + n], add);
    q[idx] += add;
}

// ---------------------------------------------------------------------------
// Flash attention, f32, v2: K/V rows are wave-uniform -> scalar (SMEM) loads,
// no LDS at all. One block per (h, b), 128 threads, thread p = tid (<100).
// Mask read as float4 per 4 keys. Online softmax with wave-uniform rescale.
// q layout: q[(b*P+p)*256 + h*16+d]; k/v: [(b*N+n)*256 + h*16+d]
// out[(b*P+p)*256 + h*16+d]  (== out_concat layout)
// ---------------------------------------------------------------------------
__global__ __launch_bounds__(128) void attn_kernel(
    const float* __restrict__ q, const float* __restrict__ k,
    const float* __restrict__ v, const float* __restrict__ mask,
    float* __restrict__ out)
{
    const int h = blockIdx.x;
    const int b = blockIdx.y;
    const int tid = threadIdx.x;
    const int p = tid;
    const int pc = (p < P_) ? p : (P_ - 1);   // clamp idle lanes to valid data

    float qreg[16];
    {
        const float* qp = &q[((size_t)(b * P_ + pc)) * 256 + h * 16];
#pragma unroll
        for (int d4 = 0; d4 < 4; ++d4) {
            float4 t = *(const float4*)&qp[d4 * 4];
            qreg[d4 * 4 + 0] = t.x; qreg[d4 * 4 + 1] = t.y;
            qreg[d4 * 4 + 2] = t.z; qreg[d4 * 4 + 3] = t.w;
        }
    }

    const float* kb = k + (size_t)b * N_ * 256 + h * 16;   // row n at kb + n*256
    const float* vb = v + (size_t)b * N_ * 256 + h * 16;
    const float* maskrow = &mask[((size_t)(b * P_ + pc)) * N_];

    float m = -INFINITY, l = 0.f;
    float acc[16];
#pragma unroll
    for (int d = 0; d < 16; ++d) acc[d] = 0.f;

    for (int g = 0; g < N_; g += 4) {
        float4 mk4 = *(const float4*)&maskrow[g];
        float mk[4] = {mk4.x, mk4.y, mk4.z, mk4.w};
        float s[4];
#pragma unroll
        for (int j = 0; j < 4; ++j) {
            const float* kr = kb + (size_t)(g + j) * 256;  // uniform address -> s_load
            float d0 = 0.f, d1 = 0.f, d2 = 0.f, d3 = 0.f;
#pragma unroll
            for (int dd = 0; dd < 4; ++dd) {
                d0 = fmaf(qreg[0  + dd], kr[0  + dd], d0);
                d1 = fmaf(qreg[4  + dd], kr[4  + dd], d1);
                d2 = fmaf(qreg[8  + dd], kr[8  + dd], d2);
                d3 = fmaf(qreg[12 + dd], kr[12 + dd], d3);
            }
            float dot = (d0 + d1) + (d2 + d3);
            s[j] = fmaf(dot, 0.25f, mk[j]);
        }
        float tmax = fmaxf(fmaxf(s[0], s[1]), fmaxf(s[2], s[3]));
        if (__any(tmax > m)) {               // wave-uniform, rarely taken late
            float mn = fmaxf(m, tmax);
            float f = EXP2F((m - mn) * L2E); // exp2(0)=1 for lanes not needing it
            l *= f;
#pragma unroll
            for (int d = 0; d < 16; ++d) acc[d] *= f;
            m = mn;
        }
#pragma unroll
        for (int j = 0; j < 4; ++j) {
            float w = EXP2F((s[j] - m) * L2E);
            l += w;
            const float* vr = vb + (size_t)(g + j) * 256;  // uniform -> s_load
#pragma unroll
            for (int d = 0; d < 16; ++d)
                acc[d] = fmaf(w, vr[d], acc[d]);
        }
    }

    if (p < P_) {
        float inv = 1.0f / l;
        float* op = &out[((size_t)(b * P_ + p)) * 256 + h * 16];
#pragma unroll
        for (int d4 = 0; d4 < 4; ++d4) {
            float4 o;
            o.x = acc[d4 * 4 + 0] * inv;
            o.y = acc[d4 * 4 + 1] * inv;
            o.z = acc[d4 * 4 + 2] * inv;
            o.w = acc[d4 * 4 + 3] * inv;
            *(float4*)&op[d4 * 4] = o;
        }
    }
}

// ---------------------------------------------------------------------------
// logits[b,p,n] = 10*tanh( (mh[b,p,:] . nodes[b,n,:]) / 16 ) + mask[b,p,n]
// A@B^T tiling: 64x64 tile, BK=32, 256 threads, 4x4 micro.
// grid = (nb=16, pb=2, b=64)
// ---------------------------------------------------------------------------
#define LBK 32
__global__ __launch_bounds__(256) void logits_kernel(
    const float* __restrict__ mh, const float* __restrict__ nodes,
    const float* __restrict__ mask, float* __restrict__ out)
{
    __shared__ float As[LBK][68];   // [k][p]  row stride 68 floats (16B-aligned)
    __shared__ float Bs[LBK][68];   // [k][n]

    const int nb = blockIdx.x, pb = blockIdx.y, b = blockIdx.z;
    const int p0 = pb * 64, n0 = nb * 64;
    const int tid = threadIdx.x;
    const int tx = tid & 15, ty = tid >> 4;

    const float* Ab = &mh[(size_t)b * P_ * EMB_];
    const float* Bb = &nodes[(size_t)b * N_ * EMB_];

    float acc[4][4];
#pragma unroll
    for (int i = 0; i < 4; ++i)
#pragma unroll
        for (int j = 0; j < 4; ++j) acc[i][j] = 0.f;

    for (int k0 = 0; k0 < EMB_; k0 += LBK) {
        // A tile: 64 rows x 32 k = 512 float4, transposed store
#pragma unroll
        for (int i = 0; i < 2; ++i) {
            int f4 = tid + i * 256;
            int r  = f4 >> 3;            // 0..63
            int c4 = (f4 & 7) << 2;      // 0..28
            int p  = p0 + r;
            float4 av = (p < P_) ? *(const float4*)&Ab[(size_t)p * EMB_ + k0 + c4]
                                 : float4{0.f, 0.f, 0.f, 0.f};
            As[c4 + 0][r] = av.x; As[c4 + 1][r] = av.y;
            As[c4 + 2][r] = av.z; As[c4 + 3][r] = av.w;
        }
        // B tile (nodes rows): 64 rows x 32 k, transposed store
#pragma unroll
        for (int i = 0; i < 2; ++i) {
            int f4 = tid + i * 256;
            int r  = f4 >> 3;
            int c4 = (f4 & 7) << 2;
            int n  = n0 + r; if (n > N_ - 1) n = N_ - 1;
            float4 bv = *(const float4*)&Bb[(size_t)n * EMB_ + k0 + c4];
            Bs[c4 + 0][r] = bv.x; Bs[c4 + 1][r] = bv.y;
            Bs[c4 + 2][r] = bv.z; Bs[c4 + 3][r] = bv.w;
        }
        __syncthreads();

#pragma unroll
        for (int kk = 0; kk < LBK; ++kk) {
            float4 a = *(const float4*)&As[kk][ty * 4];
            float4 bb = *(const float4*)&Bs[kk][tx * 4];
            float av[4] = {a.x, a.y, a.z, a.w};
            float bv[4] = {bb.x, bb.y, bb.z, bb.w};
#pragma unroll
            for (int i = 0; i < 4; ++i)
#pragma unroll
                for (int j = 0; j < 4; ++j)
                    acc[i][j] = fmaf(av[i], bv[j], acc[i][j]);
        }
        __syncthreads();
    }

#pragma unroll
    for (int i = 0; i < 4; ++i) {
        int p = p0 + ty * 4 + i;
        if (p >= P_) continue;
#pragma unroll
        for (int j = 0; j < 4; ++j) {
            int n = n0 + tx * 4 + j;
            if (n >= N_) continue;
            float x = acc[i][j] * (1.0f / 16.0f);
            // tanh(x) = 1 - 2/(exp(2x)+1), exp via exp2
            float e = EXP2F(x * (2.0f * L2E));
            float t = 1.0f - 2.0f / (e + 1.0f);
            size_t o = ((size_t)(b * P_ + p)) * N_ + n;
            out[o] = 10.0f * t + mask[o];
        }
    }
}

// ---------------------------------------------------------------------------
// In-place row softmax over N=1000. One block per row (B*P rows), 256 threads.
// ---------------------------------------------------------------------------
__global__ __launch_bounds__(256) void softmax_kernel(float* __restrict__ io)
{
    const size_t row = blockIdx.x;
    float* r = &io[row * N_];
    const int tid = threadIdx.x;
    const int wave = tid >> 6, lane = tid & 63;

    float vals[4];
    float mx = -INFINITY;
#pragma unroll
    for (int j = 0; j < 4; ++j) {
        int n = tid + j * 256;
        vals[j] = (n < N_) ? r[n] : -INFINITY;
        mx = fmaxf(mx, vals[j]);
    }
#pragma unroll
    for (int off = 32; off > 0; off >>= 1) mx = fmaxf(mx, __shfl_down(mx, off));
    __shared__ float redm[4];
    if (lane == 0) redm[wave] = mx;
    __syncthreads();
    mx = fmaxf(fmaxf(redm[0], redm[1]), fmaxf(redm[2], redm[3]));

    float sum = 0.f;
#pragma unroll
    for (int j = 0; j < 4; ++j) {
        float w = EXP2F((vals[j] - mx) * L2E);
        vals[j] = w;
        sum += w;
    }
#pragma unroll
    for (int off = 32; off > 0; off >>= 1) sum += __shfl_down(sum, off);
    __shared__ float reds[4];
    if (lane == 0) reds[wave] = sum;
    __syncthreads();
    sum = reds[0] + reds[1] + reds[2] + reds[3];

    float inv = 1.0f / sum;
#pragma unroll
    for (int j = 0; j < 4; ++j) {
        int n = tid + j * 256;
        if (n < N_) r[n] = vals[j] * inv;
    }
}

// ---------------------------------------------------------------------------
extern "C" void kernel_launch(void* const* d_in, const int* in_sizes, int n_in,
                              void* d_out, int out_size, void* d_ws, size_t ws_size,
                              hipStream_t stream)
{
    const float* lastnode = (const float*)d_in[0];   // [B,P,256]
    const float* attr     = (const float*)d_in[1];   // [B,P,4]
    const float* ctx      = (const float*)d_in[2];   // [B,1024]
    const float* mask     = (const float*)d_in[3];   // [B,P,N]
    const float* nodes    = (const float*)d_in[4];   // [B,N,256]
    const float* Wq       = (const float*)d_in[5];   // [1284,256]
    const float* Wk       = (const float*)d_in[6];   // [256,256]
    const float* Wv       = (const float*)d_in[7];   // [256,256]
    const float* Wcomb    = (const float*)d_in[8];   // [256,256]
    const float* bcomb    = (const float*)d_in[9];   // [256]
    float* out = (float*)d_out;

    // Workspace layout (floats). Total 37,699,584 floats = 150.8 MB.
    float* ws    = (float*)d_ws;
    float* kbuf  = ws;                    // 64000*256
    float* vbuf  = kbuf + 16384000;       // 64000*256
    float* qbuf  = vbuf + 16384000;       // 6400*256
    float* abuf  = qbuf + 1638400;        // 6400*256
    float* mhbuf = abuf + 1638400;        // 6400*256
    float* qcbuf = mhbuf + 1638400;       // 64*256

    // k, v projections: M=64000, N=256, K=256
    gemm128<<<dim3(500, 2), 256, 0, stream>>>(nodes, 256, Wk, 256, kbuf, 256, 256, nullptr);
    gemm128<<<dim3(500, 2), 256, 0, stream>>>(nodes, 256, Wv, 256, vbuf, 256, 256, nullptr);

    // q: main term + per-batch ctx projection + attr rank-4 fixup
    qc_kernel<<<64, 256, 0, stream>>>(ctx, Wq, qcbuf);
    gemm128<<<dim3(50, 2), 256, 0, stream>>>(lastnode, 256, Wq, 256, qbuf, 256, 256, nullptr);
    qfix_kernel<<<6400, 256, 0, stream>>>(attr, Wq, qcbuf, qbuf);

    // attention (no LDS, scalar K/V loads)
    attn_kernel<<<dim3(H_, B_), 128, 0, stream>>>(qbuf, kbuf, vbuf, mask, abuf);

    // combine
    gemm128<<<dim3(50, 2), 256, 0, stream>>>(abuf, 256, Wcomb, 256, mhbuf, 256, 256, bcomb);

    // pointer logits into d_out, then in-place softmax
    logits_kernel<<<dim3(16, 2, 64), 256, 0, stream>>>(mhbuf, nodes, mask, out);
    softmax_kernel<<<B_ * P_, 256, 0, stream>>>(out);
}

// Round 3
// 647.716 us; speedup vs baseline: 1.2587x; 1.0485x over previous
//
#include <hip/hip_runtime.h>
#include <hip/hip_bf16.h>
#include <math.h>

// Problem constants (from reference)
#define B_  64
#define P_  100
#define N_  1000
#define EMB_ 256
#define H_  16
#define D_  16
#define CTX_ 1024
#define L2E 1.44269504088896340736f

#if __has_builtin(__builtin_amdgcn_exp2f)
#define EXP2F(x) __builtin_amdgcn_exp2f(x)
#else
#define EXP2F(x) exp2f(x)
#endif

typedef __bf16 bf16_t;
typedef bf16_t bf16x8 __attribute__((ext_vector_type(8)));
typedef bf16_t bf16x4 __attribute__((ext_vector_type(4)));
typedef float  f32x4  __attribute__((ext_vector_type(4)));

// ---------------------------------------------------------------------------
// f32 -> bf16 bulk convert (4 elems/thread)
// ---------------------------------------------------------------------------
__global__ __launch_bounds__(256) void cvt_bf16_kernel(
    const float* __restrict__ in, bf16_t* __restrict__ out, int n4)
{
    int i = blockIdx.x * 256 + threadIdx.x;
    if (i >= n4) return;
    float4 v = ((const float4*)in)[i];
    bf16x4 o;
    o[0] = (bf16_t)v.x; o[1] = (bf16_t)v.y; o[2] = (bf16_t)v.z; o[3] = (bf16_t)v.w;
    ((bf16x4*)out)[i] = o;
}

// ---------------------------------------------------------------------------
// Transpose three 256x256 f32 weights -> bf16 WT[n][k]
// ---------------------------------------------------------------------------
__global__ __launch_bounds__(256) void wtrans_kernel(
    const float* __restrict__ W0, const float* __restrict__ W1, const float* __restrict__ W2,
    bf16_t* __restrict__ T0, bf16_t* __restrict__ T1, bf16_t* __restrict__ T2)
{
    __shared__ float t[32][33];
    const float* W = (blockIdx.z == 0) ? W0 : (blockIdx.z == 1) ? W1 : W2;
    bf16_t*      T = (blockIdx.z == 0) ? T0 : (blockIdx.z == 1) ? T1 : T2;
    const int n0 = blockIdx.x * 32, k0 = blockIdx.y * 32;
    const int tx = threadIdx.x & 31, ty = threadIdx.x >> 5;   // ty 0..7
#pragma unroll
    for (int i = 0; i < 4; ++i)
        t[ty + i * 8][tx] = W[(size_t)(k0 + ty + i * 8) * 256 + n0 + tx];
    __syncthreads();
#pragma unroll
    for (int i = 0; i < 4; ++i)
        T[(size_t)(n0 + ty + i * 8) * 256 + k0 + tx] = (bf16_t)t[tx][ty + i * 8];
}

// ---------------------------------------------------------------------------
// MFMA GEMM: C[M,256] = A[M,256] @ BT[256,256]^T, A/BT bf16 row-major.
// Block = 4 waves; wave w computes rows m0..m0+15, cols w*64..w*64+63.
// grid.x = M/16. No LDS. Optional bias, optional bf16 output.
// ---------------------------------------------------------------------------
template<bool BIAS, bool OUT_BF16>
__global__ __launch_bounds__(256) void mfma_gemm(
    const bf16_t* __restrict__ A, const bf16_t* __restrict__ BT,
    const float* __restrict__ bias, void* __restrict__ Cout)
{
    const int wave = threadIdx.x >> 6;
    const int lane = threadIdx.x & 63;
    const int m0 = blockIdx.x * 16;
    const int n0 = wave * 64;
    const int lr = lane & 15;
    const int lk = (lane >> 4) * 8;

    const bf16_t* ap = A  + (size_t)(m0 + lr) * 256 + lk;
    const bf16_t* bp = BT + (size_t)(n0 + lr) * 256 + lk;

    f32x4 acc[4];
#pragma unroll
    for (int j = 0; j < 4; ++j) acc[j] = (f32x4)0.f;

#pragma unroll 2
    for (int k0 = 0; k0 < 256; k0 += 32) {
        bf16x8 a = *(const bf16x8*)(ap + k0);
#pragma unroll
        for (int j = 0; j < 4; ++j) {
            bf16x8 b = *(const bf16x8*)(bp + (size_t)j * 16 * 256 + k0);
            acc[j] = __builtin_amdgcn_mfma_f32_16x16x32_bf16(a, b, acc[j], 0, 0, 0);
        }
    }

    const int crow = m0 + (lane >> 4) * 4;
#pragma unroll
    for (int j = 0; j < 4; ++j) {
        const int col = n0 + j * 16 + lr;
        const float bv = BIAS ? bias[col] : 0.f;
#pragma unroll
        for (int r = 0; r < 4; ++r) {
            float val = acc[j][r] + bv;
            if (OUT_BF16)
                ((bf16_t*)Cout)[(size_t)(crow + r) * 256 + col] = (bf16_t)val;
            else
                ((float*)Cout)[(size_t)(crow + r) * 256 + col] = val;
        }
    }
}

// ---------------------------------------------------------------------------
// qc[b][n] = sum_k ctx[b][k] * Wq[260 + k][n]   (per-batch context projection)
// ---------------------------------------------------------------------------
__global__ __launch_bounds__(256) void qc_kernel(
    const float* __restrict__ ctx, const float* __restrict__ Wq,
    float* __restrict__ qc)
{
    __shared__ float cs[CTX_];
    const int b = blockIdx.x;
    const int tid = threadIdx.x;
#pragma unroll
    for (int i = 0; i < 4; ++i) cs[tid + i * 256] = ctx[(size_t)b * CTX_ + tid + i * 256];
    __syncthreads();
    float acc = 0.f;
    const float* w = Wq + (size_t)260 * EMB_ + tid;
#pragma unroll 8
    for (int kk = 0; kk < CTX_; ++kk)
        acc = fmaf(cs[kk], w[(size_t)kk * EMB_], acc);
    qc[(size_t)b * EMB_ + tid] = acc;
}

// ---------------------------------------------------------------------------
// f32 GEMM for the q main term (M=6400, N=256, K=256), kept from R1.
// ---------------------------------------------------------------------------
#define GBM 128
#define GBN 128
#define GBK 16
__global__ __launch_bounds__(256) void gemm128(
    const float* __restrict__ A, int lda,
    const float* __restrict__ W, int ldw,
    float* __restrict__ C, int ldc, int K)
{
    __shared__ float As[GBK][GBM + 4];
    __shared__ float Bs[GBK][GBN + 4];
    const int m0 = blockIdx.x * GBM;
    const int n0 = blockIdx.y * GBN;
    const int tid = threadIdx.x;
    const int tx = tid & 15, ty = tid >> 4;

    float acc[8][8];
#pragma unroll
    for (int i = 0; i < 8; ++i)
#pragma unroll
        for (int j = 0; j < 8; ++j) acc[i][j] = 0.f;

    for (int k0 = 0; k0 < K; k0 += GBK) {
#pragma unroll
        for (int i = 0; i < 2; ++i) {
            int f4 = tid + i * 256;
            int r = f4 >> 2, c4 = (f4 & 3) << 2;
            float4 av = *(const float4*)&A[(size_t)(m0 + r) * lda + k0 + c4];
            As[c4 + 0][r] = av.x; As[c4 + 1][r] = av.y;
            As[c4 + 2][r] = av.z; As[c4 + 3][r] = av.w;
        }
#pragma unroll
        for (int i = 0; i < 2; ++i) {
            int f4 = tid + i * 256;
            int kk = f4 >> 5, c4 = (f4 & 31) << 2;
            *(float4*)&Bs[kk][c4] = *(const float4*)&W[(size_t)(k0 + kk) * ldw + n0 + c4];
        }
        __syncthreads();
#pragma unroll
        for (int kk = 0; kk < GBK; ++kk) {
            float a[8], b[8];
            float4 t;
            t = *(const float4*)&As[kk][ty * 4];      a[0]=t.x; a[1]=t.y; a[2]=t.z; a[3]=t.w;
            t = *(const float4*)&As[kk][64 + ty * 4]; a[4]=t.x; a[5]=t.y; a[6]=t.z; a[7]=t.w;
            t = *(const float4*)&Bs[kk][tx * 4];      b[0]=t.x; b[1]=t.y; b[2]=t.z; b[3]=t.w;
            t = *(const float4*)&Bs[kk][64 + tx * 4]; b[4]=t.x; b[5]=t.y; b[6]=t.z; b[7]=t.w;
#pragma unroll
            for (int i = 0; i < 8; ++i)
#pragma unroll
                for (int j = 0; j < 8; ++j)
                    acc[i][j] = fmaf(a[i], b[j], acc[i][j]);
        }
        __syncthreads();
    }
#pragma unroll
    for (int i = 0; i < 8; ++i) {
        int r = (i < 4) ? (ty * 4 + i) : (64 + ty * 4 + (i - 4));
        size_t base = (size_t)(m0 + r) * ldc + n0;
#pragma unroll
        for (int jh = 0; jh < 2; ++jh) {
            int c = jh * 64 + tx * 4;
            float4 o;
            o.x = acc[i][jh * 4 + 0]; o.y = acc[i][jh * 4 + 1];
            o.z = acc[i][jh * 4 + 2]; o.w = acc[i][jh * 4 + 3];
            *(float4*)&C[base + c] = o;
        }
    }
}

// ---------------------------------------------------------------------------
// q[m][n] += attr[m][0..3] . Wq[256..259][n]  +  qc[b][n]
// ---------------------------------------------------------------------------
__global__ __launch_bounds__(256) void qfix_kernel(
    const float* __restrict__ attr, const float* __restrict__ Wq,
    const float* __restrict__ qc, float* __restrict__ q)
{
    const int idx = blockIdx.x * 256 + threadIdx.x;
    const int n = idx & 255;
    const int m = idx >> 8;
    const int b = m / P_;
    float a0 = attr[(size_t)m * 4 + 0];
    float a1 = attr[(size_t)m * 4 + 1];
    float a2 = attr[(size_t)m * 4 + 2];
    float a3 = attr[(size_t)m * 4 + 3];
    float add = qc[(size_t)b * EMB_ + n];
    add = fmaf(a0, Wq[(size_t)256 * EMB_ + n], add);
    add = fmaf(a1, Wq[(size_t)257 * EMB_ + n], add);
    add = fmaf(a2, Wq[(size_t)258 * EMB_ + n], add);
    add = fmaf(a3, Wq[(size_t)259 * EMB_ + n], add);
    q[idx] += add;
}

// ---------------------------------------------------------------------------
// Attention, N-split x4 for occupancy. grid (H,B,4), block 128 (thread = p).
// K/V are bf16 (wave-uniform scalar reads). Writes partial m,l,acc to ws.
// ---------------------------------------------------------------------------
__global__ __launch_bounds__(128) void attn_split(
    const float* __restrict__ q, const bf16_t* __restrict__ k,
    const bf16_t* __restrict__ v, const float* __restrict__ mask,
    float* __restrict__ pml, float* __restrict__ pacc)
{
    const int h = blockIdx.x;
    const int b = blockIdx.y;
    const int s = blockIdx.z;
    const int n_lo = s * 256;
    const int n_hi = (s == 3) ? N_ : (n_lo + 256);
    const int tid = threadIdx.x;
    const int p = tid;
    const int pc = (p < P_) ? p : (P_ - 1);

    float qreg[16];
    {
        const float* qp = &q[((size_t)(b * P_ + pc)) * 256 + h * 16];
#pragma unroll
        for (int d4 = 0; d4 < 4; ++d4) {
            float4 t = *(const float4*)&qp[d4 * 4];
            qreg[d4 * 4 + 0] = t.x; qreg[d4 * 4 + 1] = t.y;
            qreg[d4 * 4 + 2] = t.z; qreg[d4 * 4 + 3] = t.w;
        }
    }

    const bf16_t* kb = k + (size_t)b * N_ * 256 + h * 16;
    const bf16_t* vb = v + (size_t)b * N_ * 256 + h * 16;
    const float* maskrow = &mask[((size_t)(b * P_ + pc)) * N_];

    float m = -INFINITY, l = 0.f;
    float acc[16];
#pragma unroll
    for (int d = 0; d < 16; ++d) acc[d] = 0.f;

    for (int g = n_lo; g < n_hi; g += 4) {
        float4 mk4 = *(const float4*)&maskrow[g];
        float mk[4] = {mk4.x, mk4.y, mk4.z, mk4.w};
        float s4[4];
#pragma unroll
        for (int j = 0; j < 4; ++j) {
            const bf16_t* kr = kb + (size_t)(g + j) * 256;  // uniform -> s_load
            float d0 = 0.f, d1 = 0.f, d2 = 0.f, d3 = 0.f;
#pragma unroll
            for (int dd = 0; dd < 4; ++dd) {
                d0 = fmaf(qreg[0  + dd], (float)kr[0  + dd], d0);
                d1 = fmaf(qreg[4  + dd], (float)kr[4  + dd], d1);
                d2 = fmaf(qreg[8  + dd], (float)kr[8  + dd], d2);
                d3 = fmaf(qreg[12 + dd], (float)kr[12 + dd], d3);
            }
            float dot = (d0 + d1) + (d2 + d3);
            s4[j] = fmaf(dot, 0.25f, mk[j]);
        }
        float tmax = fmaxf(fmaxf(s4[0], s4[1]), fmaxf(s4[2], s4[3]));
        if (__any(tmax > m)) {
            float mn = fmaxf(m, tmax);
            float f = EXP2F((m - mn) * L2E);
            l *= f;
#pragma unroll
            for (int d = 0; d < 16; ++d) acc[d] *= f;
            m = mn;
        }
#pragma unroll
        for (int j = 0; j < 4; ++j) {
            float w = EXP2F((s4[j] - m) * L2E);
            l += w;
            const bf16_t* vr = vb + (size_t)(g + j) * 256;  // uniform -> s_load
#pragma unroll
            for (int d = 0; d < 16; ++d)
                acc[d] = fmaf(w, (float)vr[d], acc[d]);
        }
    }

    if (p < P_) {
        const int idx = ((b * 16 + h) * 4 + s) * 100 + p;
        pml[idx * 2 + 0] = m;
        pml[idx * 2 + 1] = l;
#pragma unroll
        for (int d4 = 0; d4 < 4; ++d4) {
            float4 o;
            o.x = acc[d4 * 4 + 0]; o.y = acc[d4 * 4 + 1];
            o.z = acc[d4 * 4 + 2]; o.w = acc[d4 * 4 + 3];
            *(float4*)&pacc[(size_t)idx * 16 + d4 * 4] = o;
        }
    }
}

// ---------------------------------------------------------------------------
// Combine 4 partials -> normalized attention out, stored bf16 (abuf).
// grid = B*H blocks, 128 threads (thread = p).
// ---------------------------------------------------------------------------
__global__ __launch_bounds__(128) void attn_combine(
    const float* __restrict__ pml, const float* __restrict__ pacc,
    bf16_t* __restrict__ abuf)
{
    const int bh = blockIdx.x;            // b*16 + h
    const int b = bh >> 4, h = bh & 15;
    const int p = threadIdx.x;
    if (p >= P_) return;

    float ms[4], ls[4], mg = -INFINITY;
#pragma unroll
    for (int s = 0; s < 4; ++s) {
        const int idx = (bh * 4 + s) * 100 + p;
        ms[s] = pml[idx * 2 + 0];
        ls[s] = pml[idx * 2 + 1];
        mg = fmaxf(mg, ms[s]);
    }
    float L = 0.f;
    float o[16];
#pragma unroll
    for (int d = 0; d < 16; ++d) o[d] = 0.f;
#pragma unroll
    for (int s = 0; s < 4; ++s) {
        const int idx = (bh * 4 + s) * 100 + p;
        float f = EXP2F((ms[s] - mg) * L2E);
        L += ls[s] * f;
#pragma unroll
        for (int d4 = 0; d4 < 4; ++d4) {
            float4 t = *(const float4*)&pacc[(size_t)idx * 16 + d4 * 4];
            o[d4 * 4 + 0] = fmaf(t.x, f, o[d4 * 4 + 0]);
            o[d4 * 4 + 1] = fmaf(t.y, f, o[d4 * 4 + 1]);
            o[d4 * 4 + 2] = fmaf(t.z, f, o[d4 * 4 + 2]);
            o[d4 * 4 + 3] = fmaf(t.w, f, o[d4 * 4 + 3]);
        }
    }
    const float inv = 1.0f / L;
    bf16_t* op = abuf + ((size_t)(b * P_ + p)) * 256 + h * 16;
#pragma unroll
    for (int d4 = 0; d4 < 4; ++d4) {
        bf16x4 w;
        w[0] = (bf16_t)(o[d4 * 4 + 0] * inv);
        w[1] = (bf16_t)(o[d4 * 4 + 1] * inv);
        w[2] = (bf16_t)(o[d4 * 4 + 2] * inv);
        w[3] = (bf16_t)(o[d4 * 4 + 3] * inv);
        *(bf16x4*)(op + d4 * 4) = w;
    }
}

// ---------------------------------------------------------------------------
// Pointer logits via MFMA: s = 10*tanh((mh @ nodes^T)/16) + mask -> out f32.
// mh bf16 [B*100(+12 slack)][256], nodes bf16 [B*1000][256].
// grid (7, 4, 64): m-tile, n-group-quad, b. Block 256 = 4 waves.
// ---------------------------------------------------------------------------
__global__ __launch_bounds__(256) void logits_mfma(
    const bf16_t* __restrict__ mh, const bf16_t* __restrict__ nodes,
    const float* __restrict__ mask, float* __restrict__ out)
{
    const int wave = threadIdx.x >> 6;
    const int lane = threadIdx.x & 63;
    const int mt = blockIdx.x;             // 0..6  (p0 = mt*16)
    const int ngrp = blockIdx.y * 4 + wave; // 0..15 (n0 = ngrp*64)
    const int b = blockIdx.z;
    const int p0 = mt * 16;
    const int n0 = ngrp * 64;
    const int lr = lane & 15;
    const int lk = (lane >> 4) * 8;

    const bf16_t* ap = mh + ((size_t)(b * P_ + p0 + lr)) * 256 + lk;
    const bf16_t* bbase = nodes + (size_t)b * N_ * 256;

    f32x4 acc[4];
#pragma unroll
    for (int j = 0; j < 4; ++j) acc[j] = (f32x4)0.f;

    int nrow[4];
#pragma unroll
    for (int j = 0; j < 4; ++j) {
        int n = n0 + j * 16 + lr;
        nrow[j] = (n < N_) ? n : (N_ - 1);
    }

#pragma unroll 2
    for (int k0 = 0; k0 < 256; k0 += 32) {
        bf16x8 a = *(const bf16x8*)(ap + k0);
#pragma unroll
        for (int j = 0; j < 4; ++j) {
            bf16x8 bfr = *(const bf16x8*)(bbase + (size_t)nrow[j] * 256 + lk + k0);
            acc[j] = __builtin_amdgcn_mfma_f32_16x16x32_bf16(a, bfr, acc[j], 0, 0, 0);
        }
    }

    const int prow = p0 + (lane >> 4) * 4;
#pragma unroll
    for (int j = 0; j < 4; ++j) {
        const int n = n0 + j * 16 + lr;
        if (n >= N_) continue;
#pragma unroll
        for (int r = 0; r < 4; ++r) {
            const int p = prow + r;
            if (p >= P_) continue;
            float x = acc[j][r] * (1.0f / 16.0f);
            float e = EXP2F(x * (2.0f * L2E));
            float t = 1.0f - 2.0f / (e + 1.0f);
            size_t oidx = ((size_t)(b * P_ + p)) * N_ + n;
            out[oidx] = 10.0f * t + mask[oidx];
        }
    }
}

// ---------------------------------------------------------------------------
// In-place row softmax over N=1000. One block per row, 256 threads.
// ---------------------------------------------------------------------------
__global__ __launch_bounds__(256) void softmax_kernel(float* __restrict__ io)
{
    const size_t row = blockIdx.x;
    float* r = &io[row * N_];
    const int tid = threadIdx.x;
    const int wave = tid >> 6, lane = tid & 63;

    float vals[4];
    float mx = -INFINITY;
#pragma unroll
    for (int j = 0; j < 4; ++j) {
        int n = tid + j * 256;
        vals[j] = (n < N_) ? r[n] : -INFINITY;
        mx = fmaxf(mx, vals[j]);
    }
#pragma unroll
    for (int off = 32; off > 0; off >>= 1) mx = fmaxf(mx, __shfl_down(mx, off));
    __shared__ float redm[4];
    if (lane == 0) redm[wave] = mx;
    __syncthreads();
    mx = fmaxf(fmaxf(redm[0], redm[1]), fmaxf(redm[2], redm[3]));

    float sum = 0.f;
#pragma unroll
    for (int j = 0; j < 4; ++j) {
        float w = EXP2F((vals[j] - mx) * L2E);
        vals[j] = w;
        sum += w;
    }
#pragma unroll
    for (int off = 32; off > 0; off >>= 1) sum += __shfl_down(sum, off);
    __shared__ float reds[4];
    if (lane == 0) reds[wave] = sum;
    __syncthreads();
    sum = reds[0] + reds[1] + reds[2] + reds[3];

    float inv = 1.0f / sum;
#pragma unroll
    for (int j = 0; j < 4; ++j) {
        int n = tid + j * 256;
        if (n < N_) r[n] = vals[j] * inv;
    }
}

// ---------------------------------------------------------------------------
extern "C" void kernel_launch(void* const* d_in, const int* in_sizes, int n_in,
                              void* d_out, int out_size, void* d_ws, size_t ws_size,
                              hipStream_t stream)
{
    const float* lastnode = (const float*)d_in[0];   // [B,P,256]
    const float* attr     = (const float*)d_in[1];   // [B,P,4]
    const float* ctx      = (const float*)d_in[2];   // [B,1024]
    const float* mask     = (const float*)d_in[3];   // [B,P,N]
    const float* nodes    = (const float*)d_in[4];   // [B,N,256]
    const float* Wq       = (const float*)d_in[5];   // [1284,256]
    const float* Wk       = (const float*)d_in[6];   // [256,256]
    const float* Wv       = (const float*)d_in[7];   // [256,256]
    const float* Wcomb    = (const float*)d_in[8];   // [256,256]
    const float* bcomb    = (const float*)d_in[9];   // [256]
    float* out = (float*)d_out;

    // Workspace layout (offsets in floats). Total 33,701,888 f = 134.8 MB.
    float* ws = (float*)d_ws;
    bf16_t* kbuf   = (bf16_t*)(ws);                   // 16,384,000 bf16 (8,192,000 f)
    bf16_t* vbuf   = (bf16_t*)(ws + 8192000);         // 16,384,000 bf16
    float*  qbuf   = ws + 16384000;                   // 1,638,400 f
    bf16_t* nbf    = (bf16_t*)(ws + 18022400);        // 16,384,000 bf16
    bf16_t* WkT    = (bf16_t*)(ws + 26214400);        // 65,536 bf16
    bf16_t* WvT    = (bf16_t*)(ws + 26247168);        // 65,536 bf16
    bf16_t* WcombT = (bf16_t*)(ws + 26279936);        // 65,536 bf16
    float*  qcbuf  = ws + 26312704;                   // 16,384 f
    float*  pml    = ws + 26329088;                   // 819,200 f
    float*  pacc   = ws + 27148288;                   // 6,553,600 f
    // Overlays (dead-buffer reuse; stream order guarantees safety):
    bf16_t* abuf  = vbuf;                             // written after vbuf's last read
    bf16_t* mhbuf = kbuf;                             // written after kbuf's last read
                                                      // (6412 rows incl. 12 slack)

    // 1) nodes -> bf16 (also the logits B operand)
    cvt_bf16_kernel<<<16000, 256, 0, stream>>>(nodes, nbf, 4096000);

    // 2) weight transposes -> bf16
    wtrans_kernel<<<dim3(8, 8, 3), 256, 0, stream>>>(Wk, Wv, Wcomb, WkT, WvT, WcombT);

    // 3) q pipeline (f32)
    qc_kernel<<<64, 256, 0, stream>>>(ctx, Wq, qcbuf);
    gemm128<<<dim3(50, 2), 256, 0, stream>>>(lastnode, 256, Wq, 256, qbuf, 256, 256);
    qfix_kernel<<<6400, 256, 0, stream>>>(attr, Wq, qcbuf, qbuf);

    // 4) k, v projections (MFMA, bf16 out)
    mfma_gemm<false, true><<<4000, 256, 0, stream>>>(nbf, WkT, nullptr, kbuf);
    mfma_gemm<false, true><<<4000, 256, 0, stream>>>(nbf, WvT, nullptr, vbuf);

    // 5) attention: split-N partials + combine (abuf bf16)
    attn_split<<<dim3(H_, B_, 4), 128, 0, stream>>>(qbuf, kbuf, vbuf, mask, pml, pacc);
    attn_combine<<<B_ * H_, 128, 0, stream>>>(pml, pacc, abuf);

    // 6) combine projection (MFMA, bias, bf16 out into mhbuf)
    mfma_gemm<true, true><<<400, 256, 0, stream>>>(abuf, WcombT, bcomb, mhbuf);

    // 7) pointer logits (MFMA) + softmax
    logits_mfma<<<dim3(7, 4, 64), 256, 0, stream>>>(mhbuf, nbf, mask, out);
    softmax_kernel<<<B_ * P_, 256, 0, stream>>>(out);
}

// Round 4
// 484.254 us; speedup vs baseline: 1.6835x; 1.3376x over previous
//
#include <hip/hip_runtime.h>
#include <hip/hip_bf16.h>
#include <math.h>

// Problem constants (from reference)
#define B_  64
#define P_  100
#define N_  1000
#define EMB_ 256
#define H_  16
#define D_  16
#define CTX_ 1024
#define L2E 1.44269504088896340736f

#if __has_builtin(__builtin_amdgcn_exp2f)
#define EXP2F(x) __builtin_amdgcn_exp2f(x)
#else
#define EXP2F(x) exp2f(x)
#endif

typedef __bf16 bf16_t;
typedef bf16_t bf16x8 __attribute__((ext_vector_type(8)));
typedef bf16_t bf16x4 __attribute__((ext_vector_type(4)));
typedef float  f32x4  __attribute__((ext_vector_type(4)));

// v_mfma_f32_16x16x16_bf16 via inline asm (no builtin assumed on gfx950).
// Hazards handled manually: s_nop 1 covers VALU-write -> MFMA-read (2 states).
// Callers must put >=11 wait states before VALU reads of c (we use s_nop 7+3
// in the rare rescale branch and the epilogue only).
__device__ __forceinline__ void pv_mfma16(bf16x4 a, bf16x4 b, f32x4& c)
{
    asm volatile("s_nop 1\n\tv_mfma_f32_16x16x16_bf16 %0, %1, %2, %0"
                 : "+v"(c) : "v"(a), "v"(b));
}

// ---------------------------------------------------------------------------
// f32 -> bf16 bulk convert (4 elems/thread)
// ---------------------------------------------------------------------------
__global__ __launch_bounds__(256) void cvt_bf16_kernel(
    const float* __restrict__ in, bf16_t* __restrict__ out, int n4)
{
    int i = blockIdx.x * 256 + threadIdx.x;
    if (i >= n4) return;
    float4 v = ((const float4*)in)[i];
    bf16x4 o;
    o[0] = (bf16_t)v.x; o[1] = (bf16_t)v.y; o[2] = (bf16_t)v.z; o[3] = (bf16_t)v.w;
    ((bf16x4*)out)[i] = o;
}

// ---------------------------------------------------------------------------
// Transpose three 256x256 f32 weights -> bf16 WT[n][k]
// ---------------------------------------------------------------------------
__global__ __launch_bounds__(256) void wtrans_kernel(
    const float* __restrict__ W0, const float* __restrict__ W1, const float* __restrict__ W2,
    bf16_t* __restrict__ T0, bf16_t* __restrict__ T1, bf16_t* __restrict__ T2)
{
    __shared__ float t[32][33];
    const float* W = (blockIdx.z == 0) ? W0 : (blockIdx.z == 1) ? W1 : W2;
    bf16_t*      T = (blockIdx.z == 0) ? T0 : (blockIdx.z == 1) ? T1 : T2;
    const int n0 = blockIdx.x * 32, k0 = blockIdx.y * 32;
    const int tx = threadIdx.x & 31, ty = threadIdx.x >> 5;   // ty 0..7
#pragma unroll
    for (int i = 0; i < 4; ++i)
        t[ty + i * 8][tx] = W[(size_t)(k0 + ty + i * 8) * 256 + n0 + tx];
    __syncthreads();
#pragma unroll
    for (int i = 0; i < 4; ++i)
        T[(size_t)(n0 + ty + i * 8) * 256 + k0 + tx] = (bf16_t)t[tx][ty + i * 8];
}

// ---------------------------------------------------------------------------
// MFMA GEMM: C[M,256] = A[M,256] @ BT[256,256]^T, A/BT bf16 row-major.
// Block = 4 waves; wave w computes rows m0..m0+15, cols w*64..w*64+63.
// grid.x = M/16. No LDS. Optional bias, optional bf16 output.
// ---------------------------------------------------------------------------
template<bool BIAS, bool OUT_BF16>
__global__ __launch_bounds__(256) void mfma_gemm(
    const bf16_t* __restrict__ A, const bf16_t* __restrict__ BT,
    const float* __restrict__ bias, void* __restrict__ Cout)
{
    const int wave = threadIdx.x >> 6;
    const int lane = threadIdx.x & 63;
    const int m0 = blockIdx.x * 16;
    const int n0 = wave * 64;
    const int lr = lane & 15;
    const int lk = (lane >> 4) * 8;

    const bf16_t* ap = A  + (size_t)(m0 + lr) * 256 + lk;
    const bf16_t* bp = BT + (size_t)(n0 + lr) * 256 + lk;

    f32x4 acc[4];
#pragma unroll
    for (int j = 0; j < 4; ++j) acc[j] = (f32x4)0.f;

#pragma unroll 2
    for (int k0 = 0; k0 < 256; k0 += 32) {
        bf16x8 a = *(const bf16x8*)(ap + k0);
#pragma unroll
        for (int j = 0; j < 4; ++j) {
            bf16x8 b = *(const bf16x8*)(bp + (size_t)j * 16 * 256 + k0);
            acc[j] = __builtin_amdgcn_mfma_f32_16x16x32_bf16(a, b, acc[j], 0, 0, 0);
        }
    }

    const int crow = m0 + (lane >> 4) * 4;
#pragma unroll
    for (int j = 0; j < 4; ++j) {
        const int col = n0 + j * 16 + lr;
        const float bv = BIAS ? bias[col] : 0.f;
#pragma unroll
        for (int r = 0; r < 4; ++r) {
            float val = acc[j][r] + bv;
            if (OUT_BF16)
                ((bf16_t*)Cout)[(size_t)(crow + r) * 256 + col] = (bf16_t)val;
            else
                ((float*)Cout)[(size_t)(crow + r) * 256 + col] = val;
        }
    }
}

// ---------------------------------------------------------------------------
// qc partials: qcpart[kc][b][n] = sum_{k in chunk kc} ctx[b][k]*Wq[260+k][n]
// grid (64, 4). ctx element is wave-uniform -> scalar loads.
// ---------------------------------------------------------------------------
__global__ __launch_bounds__(256) void qc_kernel(
    const float* __restrict__ ctx, const float* __restrict__ Wq,
    float* __restrict__ qcpart)
{
    const int b = blockIdx.x;
    const int kc = blockIdx.y;
    const int tid = threadIdx.x;
    const float* c = ctx + (size_t)b * CTX_ + kc * 256;
    const float* w = Wq + (size_t)(260 + kc * 256) * EMB_ + tid;
    float acc = 0.f;
#pragma unroll 8
    for (int kk = 0; kk < 256; ++kk)
        acc = fmaf(c[kk], w[(size_t)kk * EMB_], acc);
    qcpart[((size_t)kc * 64 + b) * EMB_ + tid] = acc;
}

// ---------------------------------------------------------------------------
// f32 GEMM for the q main term (M=6400, N=256, K=256).
// ---------------------------------------------------------------------------
#define GBM 128
#define GBN 128
#define GBK 16
__global__ __launch_bounds__(256) void gemm128(
    const float* __restrict__ A, int lda,
    const float* __restrict__ W, int ldw,
    float* __restrict__ C, int ldc, int K)
{
    __shared__ float As[GBK][GBM + 4];
    __shared__ float Bs[GBK][GBN + 4];
    const int m0 = blockIdx.x * GBM;
    const int n0 = blockIdx.y * GBN;
    const int tid = threadIdx.x;
    const int tx = tid & 15, ty = tid >> 4;

    float acc[8][8];
#pragma unroll
    for (int i = 0; i < 8; ++i)
#pragma unroll
        for (int j = 0; j < 8; ++j) acc[i][j] = 0.f;

    for (int k0 = 0; k0 < K; k0 += GBK) {
#pragma unroll
        for (int i = 0; i < 2; ++i) {
            int f4 = tid + i * 256;
            int r = f4 >> 2, c4 = (f4 & 3) << 2;
            float4 av = *(const float4*)&A[(size_t)(m0 + r) * lda + k0 + c4];
            As[c4 + 0][r] = av.x; As[c4 + 1][r] = av.y;
            As[c4 + 2][r] = av.z; As[c4 + 3][r] = av.w;
        }
#pragma unroll
        for (int i = 0; i < 2; ++i) {
            int f4 = tid + i * 256;
            int kk = f4 >> 5, c4 = (f4 & 31) << 2;
            *(float4*)&Bs[kk][c4] = *(const float4*)&W[(size_t)(k0 + kk) * ldw + n0 + c4];
        }
        __syncthreads();
#pragma unroll
        for (int kk = 0; kk < GBK; ++kk) {
            float a[8], b[8];
            float4 t;
            t = *(const float4*)&As[kk][ty * 4];      a[0]=t.x; a[1]=t.y; a[2]=t.z; a[3]=t.w;
            t = *(const float4*)&As[kk][64 + ty * 4]; a[4]=t.x; a[5]=t.y; a[6]=t.z; a[7]=t.w;
            t = *(const float4*)&Bs[kk][tx * 4];      b[0]=t.x; b[1]=t.y; b[2]=t.z; b[3]=t.w;
            t = *(const float4*)&Bs[kk][64 + tx * 4]; b[4]=t.x; b[5]=t.y; b[6]=t.z; b[7]=t.w;
#pragma unroll
            for (int i = 0; i < 8; ++i)
#pragma unroll
                for (int j = 0; j < 8; ++j)
                    acc[i][j] = fmaf(a[i], b[j], acc[i][j]);
        }
        __syncthreads();
    }
#pragma unroll
    for (int i = 0; i < 8; ++i) {
        int r = (i < 4) ? (ty * 4 + i) : (64 + ty * 4 + (i - 4));
        size_t base = (size_t)(m0 + r) * ldc + n0;
#pragma unroll
        for (int jh = 0; jh < 2; ++jh) {
            int c = jh * 64 + tx * 4;
            float4 o;
            o.x = acc[i][jh * 4 + 0]; o.y = acc[i][jh * 4 + 1];
            o.z = acc[i][jh * 4 + 2]; o.w = acc[i][jh * 4 + 3];
            *(float4*)&C[base + c] = o;
        }
    }
}

// ---------------------------------------------------------------------------
// q[m][n] += attr[m][0..3] . Wq[256..259][n]  +  sum_kc qcpart[kc][b][n]
// ---------------------------------------------------------------------------
__global__ __launch_bounds__(256) void qfix_kernel(
    const float* __restrict__ attr, const float* __restrict__ Wq,
    const float* __restrict__ qcpart, float* __restrict__ q)
{
    const int idx = blockIdx.x * 256 + threadIdx.x;
    const int n = idx & 255;
    const int m = idx >> 8;
    const int b = m / P_;
    float a0 = attr[(size_t)m * 4 + 0];
    float a1 = attr[(size_t)m * 4 + 1];
    float a2 = attr[(size_t)m * 4 + 2];
    float a3 = attr[(size_t)m * 4 + 3];
    float add = 0.f;
#pragma unroll
    for (int kc = 0; kc < 4; ++kc)
        add += qcpart[((size_t)kc * 64 + b) * EMB_ + n];
    add = fmaf(a0, Wq[(size_t)256 * EMB_ + n], add);
    add = fmaf(a1, Wq[(size_t)257 * EMB_ + n], add);
    add = fmaf(a2, Wq[(size_t)258 * EMB_ + n], add);
    add = fmaf(a3, Wq[(size_t)259 * EMB_ + n], add);
    q[idx] += add;
}

// ---------------------------------------------------------------------------
// MFMA flash attention. Grid (2, H, B), block 256 = 4 waves.
// Wave handles query tile mtile = blockIdx.x*4 + wave (0..6; 7 exits).
// S^T tile per 16-key chunk: mfma_16x16x32(A=K rows, B=Q cols) with upper
// 16 k (d-dim) zero-padded -> lane holds S^T[n=4*lg+r][p=lr].
// PV: v_mfma_16x16x16(A=V^T, B=P^T) accumulates out^T[d=4*lg+r][p=lr];
// P^T B-frag layout == S^T C/D layout (no lane relayout needed).
// ---------------------------------------------------------------------------
struct AttnState { float m, l; f32x4 acc; };

template<bool TAIL>
__device__ __forceinline__ void attn_chunk(
    int n0, const bf16_t* __restrict__ kb, const bf16_t* __restrict__ vb,
    const float* __restrict__ maskrow, bf16x8 qfrag, int lr, int lg,
    AttnState& st)
{
    // K A-frag: row n = n0+lr, k(d) = 8*(lg&1)+i ; zero for lg>=2
    int nk = n0 + lr;
    if (TAIL) nk = (nk < N_) ? nk : (N_ - 1);
    bf16x8 ak = *(const bf16x8*)(kb + (size_t)nk * 256 + (lg & 1) * 8);
    if (lg >= 2) ak = (bf16x8)(bf16_t)0.0f;

    f32x4 sc = __builtin_amdgcn_mfma_f32_16x16x32_bf16(ak, qfrag, (f32x4)0.f, 0, 0, 0);

    // scores + mask (lane's 4 keys n = n0+4*lg+r, query p = lr)
    int nm = n0 + 4 * lg;
    if (TAIL) nm = (nm < 996) ? nm : 996;
    float4 mk = *(const float4*)&maskrow[nm];
    float s0 = fmaf(sc[0], 0.25f, mk.x);
    float s1 = fmaf(sc[1], 0.25f, mk.y);
    float s2 = fmaf(sc[2], 0.25f, mk.z);
    float s3 = fmaf(sc[3], 0.25f, mk.w);
    if (TAIL) {
        if (n0 + 4 * lg + 0 >= N_) s0 = -3.0e38f;
        if (n0 + 4 * lg + 1 >= N_) s1 = -3.0e38f;
        if (n0 + 4 * lg + 2 >= N_) s2 = -3.0e38f;
        if (n0 + 4 * lg + 3 >= N_) s3 = -3.0e38f;
    }

    // row max across the 4 lanes sharing lr
    float tmax = fmaxf(fmaxf(s0, s1), fmaxf(s2, s3));
    tmax = fmaxf(tmax, __shfl_xor(tmax, 16));
    tmax = fmaxf(tmax, __shfl_xor(tmax, 32));
    float mn = fmaxf(st.m, tmax);
    if (__any(mn > st.m)) {
        // VALU read of asm-mfma-written acc: cover MFMA->VALU hazard
        asm volatile("s_nop 7\n\ts_nop 3");
        float f = EXP2F((st.m - mn) * L2E);   // first chunk: exp2(-inf)=0
        st.l *= f;
        st.acc *= f;
        st.m = mn;
    }
    float w0 = EXP2F((s0 - st.m) * L2E);
    float w1 = EXP2F((s1 - st.m) * L2E);
    float w2 = EXP2F((s2 - st.m) * L2E);
    float w3 = EXP2F((s3 - st.m) * L2E);
    st.l += (w0 + w1) + (w2 + w3);
    bf16x4 pb;
    pb[0] = (bf16_t)w0; pb[1] = (bf16_t)w1; pb[2] = (bf16_t)w2; pb[3] = (bf16_t)w3;

    // V^T A-frag: row d = lr, k(n) = 4*lg+i  -> V[n0+4lg+i][d=lr]
    bf16x4 av;
#pragma unroll
    for (int i = 0; i < 4; ++i) {
        int nn = n0 + 4 * lg + i;
        if (TAIL) nn = (nn < N_) ? nn : (N_ - 1);   // w=0 kills contribution
        av[i] = vb[(size_t)nn * 256 + lr];
    }
    pv_mfma16(av, pb, st.acc);
}

__global__ __launch_bounds__(256) void attn_mfma(
    const float* __restrict__ q, const bf16_t* __restrict__ k,
    const bf16_t* __restrict__ v, const float* __restrict__ mask,
    bf16_t* __restrict__ abuf)
{
    const int wave = threadIdx.x >> 6;
    const int lane = threadIdx.x & 63;
    const int mtile = blockIdx.x * 4 + wave;
    if (mtile >= 7) return;                 // wave-uniform exit
    const int h = blockIdx.y;
    const int b = blockIdx.z;
    const int p0 = mtile * 16;
    const int lr = lane & 15;
    const int lg = lane >> 4;

    // Q B-frag (x32): col p = lr, k(d) = 8*lg+i ; zero for lg>=2
    const int pq = (p0 + lr < P_) ? (p0 + lr) : (P_ - 1);
    bf16x8 qfrag = (bf16x8)(bf16_t)0.0f;
    if (lg < 2) {
        const float* qp = q + ((size_t)b * P_ + pq) * 256 + h * 16 + lg * 8;
        float4 q0 = *(const float4*)qp;
        float4 q1 = *(const float4*)(qp + 4);
        qfrag[0] = (bf16_t)q0.x; qfrag[1] = (bf16_t)q0.y;
        qfrag[2] = (bf16_t)q0.z; qfrag[3] = (bf16_t)q0.w;
        qfrag[4] = (bf16_t)q1.x; qfrag[5] = (bf16_t)q1.y;
        qfrag[6] = (bf16_t)q1.z; qfrag[7] = (bf16_t)q1.w;
    }

    const bf16_t* kb = k + ((size_t)b * N_) * 256 + h * 16;
    const bf16_t* vb = v + ((size_t)b * N_) * 256 + h * 16;
    const float* maskrow = mask + ((size_t)b * P_ + pq) * N_;

    AttnState st;
    st.m = -INFINITY;
    st.l = 0.f;
    st.acc = (f32x4)0.f;

    for (int n0 = 0; n0 < 992; n0 += 16)
        attn_chunk<false>(n0, kb, vb, maskrow, qfrag, lr, lg, st);
    attn_chunk<true>(992, kb, vb, maskrow, qfrag, lr, lg, st);

    // row sum of l across the 4 lanes sharing lr
    float L = st.l + __shfl_xor(st.l, 16);
    L += __shfl_xor(L, 32);

    if (p0 + lr < P_) {
        asm volatile("s_nop 7\n\ts_nop 3");   // MFMA->VALU read of acc
        float inv = 1.0f / L;
        bf16x4 o;
        o[0] = (bf16_t)(st.acc[0] * inv);
        o[1] = (bf16_t)(st.acc[1] * inv);
        o[2] = (bf16_t)(st.acc[2] * inv);
        o[3] = (bf16_t)(st.acc[3] * inv);
        // out^T: lane holds out[p=lr][d=4*lg+r]
        *(bf16x4*)(abuf + ((size_t)b * P_ + p0 + lr) * 256 + h * 16 + 4 * lg) = o;
    }
}

// ---------------------------------------------------------------------------
// Pointer logits via MFMA: s = 10*tanh((mh @ nodes^T)/16) + mask -> out f32.
// grid (7, 4, 64): m-tile, n-group-quad, b. Block 256 = 4 waves.
// ---------------------------------------------------------------------------
__global__ __launch_bounds__(256) void logits_mfma(
    const bf16_t* __restrict__ mh, const bf16_t* __restrict__ nodes,
    const float* __restrict__ mask, float* __restrict__ out)
{
    const int wave = threadIdx.x >> 6;
    const int lane = threadIdx.x & 63;
    const int mt = blockIdx.x;
    const int ngrp = blockIdx.y * 4 + wave;
    const int b = blockIdx.z;
    const int p0 = mt * 16;
    const int n0 = ngrp * 64;
    const int lr = lane & 15;
    const int lk = (lane >> 4) * 8;

    const bf16_t* ap = mh + ((size_t)(b * P_) + p0 + lr) * 256 + lk;
    const bf16_t* bbase = nodes + (size_t)b * N_ * 256;

    f32x4 acc[4];
#pragma unroll
    for (int j = 0; j < 4; ++j) acc[j] = (f32x4)0.f;

    int nrow[4];
#pragma unroll
    for (int j = 0; j < 4; ++j) {
        int n = n0 + j * 16 + lr;
        nrow[j] = (n < N_) ? n : (N_ - 1);
    }

#pragma unroll 2
    for (int k0 = 0; k0 < 256; k0 += 32) {
        bf16x8 a = *(const bf16x8*)(ap + k0);
#pragma unroll
        for (int j = 0; j < 4; ++j) {
            bf16x8 bfr = *(const bf16x8*)(bbase + (size_t)nrow[j] * 256 + lk + k0);
            acc[j] = __builtin_amdgcn_mfma_f32_16x16x32_bf16(a, bfr, acc[j], 0, 0, 0);
        }
    }

    const int prow = p0 + (lane >> 4) * 4;
#pragma unroll
    for (int j = 0; j < 4; ++j) {
        const int n = n0 + j * 16 + lr;
        if (n >= N_) continue;
#pragma unroll
        for (int r = 0; r < 4; ++r) {
            const int p = prow + r;
            if (p >= P_) continue;
            float x = acc[j][r] * (1.0f / 16.0f);
            float e = EXP2F(x * (2.0f * L2E));
            float t = 1.0f - 2.0f / (e + 1.0f);
            size_t oidx = ((size_t)(b * P_ + p)) * N_ + n;
            out[oidx] = 10.0f * t + mask[oidx];
        }
    }
}

// ---------------------------------------------------------------------------
// In-place row softmax over N=1000. One block per row, 256 threads.
// ---------------------------------------------------------------------------
__global__ __launch_bounds__(256) void softmax_kernel(float* __restrict__ io)
{
    const size_t row = blockIdx.x;
    float* r = &io[row * N_];
    const int tid = threadIdx.x;
    const int wave = tid >> 6, lane = tid & 63;

    float vals[4];
    float mx = -INFINITY;
#pragma unroll
    for (int j = 0; j < 4; ++j) {
        int n = tid + j * 256;
        vals[j] = (n < N_) ? r[n] : -INFINITY;
        mx = fmaxf(mx, vals[j]);
    }
#pragma unroll
    for (int off = 32; off > 0; off >>= 1) mx = fmaxf(mx, __shfl_down(mx, off));
    __shared__ float redm[4];
    if (lane == 0) redm[wave] = mx;
    __syncthreads();
    mx = fmaxf(fmaxf(redm[0], redm[1]), fmaxf(redm[2], redm[3]));

    float sum = 0.f;
#pragma unroll
    for (int j = 0; j < 4; ++j) {
        float w = EXP2F((vals[j] - mx) * L2E);
        vals[j] = w;
        sum += w;
    }
#pragma unroll
    for (int off = 32; off > 0; off >>= 1) sum += __shfl_down(sum, off);
    __shared__ float reds[4];
    if (lane == 0) reds[wave] = sum;
    __syncthreads();
    sum = reds[0] + reds[1] + reds[2] + reds[3];

    float inv = 1.0f / sum;
#pragma unroll
    for (int j = 0; j < 4; ++j) {
        int n = tid + j * 256;
        if (n < N_) r[n] = vals[j] * inv;
    }
}

// ---------------------------------------------------------------------------
extern "C" void kernel_launch(void* const* d_in, const int* in_sizes, int n_in,
                              void* d_out, int out_size, void* d_ws, size_t ws_size,
                              hipStream_t stream)
{
    const float* lastnode = (const float*)d_in[0];   // [B,P,256]
    const float* attr     = (const float*)d_in[1];   // [B,P,4]
    const float* ctx      = (const float*)d_in[2];   // [B,1024]
    const float* mask     = (const float*)d_in[3];   // [B,P,N]
    const float* nodes    = (const float*)d_in[4];   // [B,N,256]
    const float* Wq       = (const float*)d_in[5];   // [1284,256]
    const float* Wk       = (const float*)d_in[6];   // [256,256]
    const float* Wv       = (const float*)d_in[7];   // [256,256]
    const float* Wcomb    = (const float*)d_in[8];   // [256,256]
    const float* bcomb    = (const float*)d_in[9];   // [256]
    float* out = (float*)d_out;

    // Workspace layout (offsets in floats). Total 27,197,440 f = 108.8 MB.
    float* ws = (float*)d_ws;
    bf16_t* kbuf   = (bf16_t*)(ws);                   // 16,384,000 bf16
    bf16_t* vbuf   = (bf16_t*)(ws + 8192000);         // 16,384,000 bf16
    float*  qbuf   = ws + 16384000;                   // 1,638,400 f
    bf16_t* nbf    = (bf16_t*)(ws + 18022400);        // 16,384,000 bf16
    bf16_t* WkT    = (bf16_t*)(ws + 26214400);        // 65,536 bf16
    bf16_t* WvT    = (bf16_t*)(ws + 26247168);        // 65,536 bf16
    bf16_t* WcombT = (bf16_t*)(ws + 26279936);        // 65,536 bf16
    float*  qcpart = ws + 26312704;                   // 65,536 f (4x64x256)
    bf16_t* abuf   = (bf16_t*)(ws + 26378240);        // 1,638,400 bf16
    // Overlay: mhbuf reuses kbuf (K dead after attn_mfma); logits reads rows
    // up to b*100+111 -> slack is inside kbuf's 16.4M elements (finite stale K).
    bf16_t* mhbuf = kbuf;

    // 1) nodes -> bf16 (also the logits B operand)
    cvt_bf16_kernel<<<16000, 256, 0, stream>>>(nodes, nbf, 4096000);

    // 2) weight transposes -> bf16
    wtrans_kernel<<<dim3(8, 8, 3), 256, 0, stream>>>(Wk, Wv, Wcomb, WkT, WvT, WcombT);

    // 3) q pipeline (f32)
    qc_kernel<<<dim3(64, 4), 256, 0, stream>>>(ctx, Wq, qcpart);
    gemm128<<<dim3(50, 2), 256, 0, stream>>>(lastnode, 256, Wq, 256, qbuf, 256, 256);
    qfix_kernel<<<6400, 256, 0, stream>>>(attr, Wq, qcpart, qbuf);

    // 4) k, v projections (MFMA, bf16 out)
    mfma_gemm<false, true><<<4000, 256, 0, stream>>>(nbf, WkT, nullptr, kbuf);
    mfma_gemm<false, true><<<4000, 256, 0, stream>>>(nbf, WvT, nullptr, vbuf);

    // 5) fused MFMA flash attention -> abuf (bf16)
    attn_mfma<<<dim3(2, H_, B_), 256, 0, stream>>>(qbuf, kbuf, vbuf, mask, abuf);

    // 6) combine projection (MFMA, bias, bf16 out into mhbuf)
    mfma_gemm<true, true><<<400, 256, 0, stream>>>(abuf, WcombT, bcomb, mhbuf);

    // 7) pointer logits (MFMA) + softmax
    logits_mfma<<<dim3(7, 4, 64), 256, 0, stream>>>(mhbuf, nbf, mask, out);
    softmax_kernel<<<B_ * P_, 256, 0, stream>>>(out);
}

// Round 5
// 379.078 us; speedup vs baseline: 2.1507x; 1.2775x over previous
//
#include <hip/hip_runtime.h>
#include <hip/hip_bf16.h>
#include <math.h>

// Problem constants (from reference)
#define B_  64
#define P_  100
#define N_  1000
#define EMB_ 256
#define H_  16
#define D_  16
#define CTX_ 1024
#define L2E 1.44269504088896340736f

#if __has_builtin(__builtin_amdgcn_exp2f)
#define EXP2F(x) __builtin_amdgcn_exp2f(x)
#else
#define EXP2F(x) exp2f(x)
#endif

typedef __bf16 bf16_t;
typedef bf16_t bf16x8 __attribute__((ext_vector_type(8)));
typedef bf16_t bf16x4 __attribute__((ext_vector_type(4)));
typedef float  f32x4  __attribute__((ext_vector_type(4)));

// v_mfma_f32_16x16x16_bf16 via inline asm (no builtin assumed on gfx950).
// s_nop 1 covers VALU-write -> MFMA-read (2 states). Callers place >=11
// wait states before VALU reads of c (s_nop 7+3 in rescale + epilogue).
__device__ __forceinline__ void pv_mfma16(bf16x4 a, bf16x4 b, f32x4& c)
{
    asm volatile("s_nop 1\n\tv_mfma_f32_16x16x16_bf16 %0, %1, %2, %0"
                 : "+v"(c) : "v"(a), "v"(b));
}

// ---------------------------------------------------------------------------
// f32 -> bf16 bulk convert (4 elems/thread)
// ---------------------------------------------------------------------------
__global__ __launch_bounds__(256) void cvt_bf16_kernel(
    const float* __restrict__ in, bf16_t* __restrict__ out, int n4)
{
    int i = blockIdx.x * 256 + threadIdx.x;
    if (i >= n4) return;
    float4 v = ((const float4*)in)[i];
    bf16x4 o;
    o[0] = (bf16_t)v.x; o[1] = (bf16_t)v.y; o[2] = (bf16_t)v.z; o[3] = (bf16_t)v.w;
    ((bf16x4*)out)[i] = o;
}

// ---------------------------------------------------------------------------
// Transpose three 256x256 f32 weights -> bf16 WT[n][k]
// ---------------------------------------------------------------------------
__global__ __launch_bounds__(256) void wtrans_kernel(
    const float* __restrict__ W0, const float* __restrict__ W1, const float* __restrict__ W2,
    bf16_t* __restrict__ T0, bf16_t* __restrict__ T1, bf16_t* __restrict__ T2)
{
    __shared__ float t[32][33];
    const float* W = (blockIdx.z == 0) ? W0 : (blockIdx.z == 1) ? W1 : W2;
    bf16_t*      T = (blockIdx.z == 0) ? T0 : (blockIdx.z == 1) ? T1 : T2;
    const int n0 = blockIdx.x * 32, k0 = blockIdx.y * 32;
    const int tx = threadIdx.x & 31, ty = threadIdx.x >> 5;   // ty 0..7
#pragma unroll
    for (int i = 0; i < 4; ++i)
        t[ty + i * 8][tx] = W[(size_t)(k0 + ty + i * 8) * 256 + n0 + tx];
    __syncthreads();
#pragma unroll
    for (int i = 0; i < 4; ++i)
        T[(size_t)(n0 + ty + i * 8) * 256 + k0 + tx] = (bf16_t)t[tx][ty + i * 8];
}

// ---------------------------------------------------------------------------
// MFMA GEMM: C[M,256] = A[M,256] @ BT[256,256]^T, A/BT bf16 row-major.
// Block = 4 waves; wave w computes rows m0..m0+15, cols w*64..w*64+63.
// grid.x = M/16. No LDS. Optional bias, optional bf16 output.
// ---------------------------------------------------------------------------
template<bool BIAS, bool OUT_BF16>
__global__ __launch_bounds__(256) void mfma_gemm(
    const bf16_t* __restrict__ A, const bf16_t* __restrict__ BT,
    const float* __restrict__ bias, void* __restrict__ Cout)
{
    const int wave = threadIdx.x >> 6;
    const int lane = threadIdx.x & 63;
    const int m0 = blockIdx.x * 16;
    const int n0 = wave * 64;
    const int lr = lane & 15;
    const int lk = (lane >> 4) * 8;

    const bf16_t* ap = A  + (size_t)(m0 + lr) * 256 + lk;
    const bf16_t* bp = BT + (size_t)(n0 + lr) * 256 + lk;

    f32x4 acc[4];
#pragma unroll
    for (int j = 0; j < 4; ++j) acc[j] = (f32x4)0.f;

#pragma unroll 2
    for (int k0 = 0; k0 < 256; k0 += 32) {
        bf16x8 a = *(const bf16x8*)(ap + k0);
#pragma unroll
        for (int j = 0; j < 4; ++j) {
            bf16x8 b = *(const bf16x8*)(bp + (size_t)j * 16 * 256 + k0);
            acc[j] = __builtin_amdgcn_mfma_f32_16x16x32_bf16(a, b, acc[j], 0, 0, 0);
        }
    }

    const int crow = m0 + (lane >> 4) * 4;
#pragma unroll
    for (int j = 0; j < 4; ++j) {
        const int col = n0 + j * 16 + lr;
        const float bv = BIAS ? bias[col] : 0.f;
#pragma unroll
        for (int r = 0; r < 4; ++r) {
            float val = acc[j][r] + bv;
            if (OUT_BF16)
                ((bf16_t*)Cout)[(size_t)(crow + r) * 256 + col] = (bf16_t)val;
            else
                ((float*)Cout)[(size_t)(crow + r) * 256 + col] = val;
        }
    }
}

// ---------------------------------------------------------------------------
// qc partials: qcpart[kc][b][n] = sum_{k in chunk kc} ctx[b][k]*Wq[260+k][n]
// grid (64, 4). ctx element is wave-uniform -> scalar loads.
// ---------------------------------------------------------------------------
__global__ __launch_bounds__(256) void qc_kernel(
    const float* __restrict__ ctx, const float* __restrict__ Wq,
    float* __restrict__ qcpart)
{
    const int b = blockIdx.x;
    const int kc = blockIdx.y;
    const int tid = threadIdx.x;
    const float* c = ctx + (size_t)b * CTX_ + kc * 256;
    const float* w = Wq + (size_t)(260 + kc * 256) * EMB_ + tid;
    float acc = 0.f;
#pragma unroll 8
    for (int kk = 0; kk < 256; ++kk)
        acc = fmaf(c[kk], w[(size_t)kk * EMB_], acc);
    qcpart[((size_t)kc * 64 + b) * EMB_ + tid] = acc;
}

// ---------------------------------------------------------------------------
// f32 GEMM for the q main term (M=6400, N=256, K=256).
// ---------------------------------------------------------------------------
#define GBM 128
#define GBN 128
#define GBK 16
__global__ __launch_bounds__(256) void gemm128(
    const float* __restrict__ A, int lda,
    const float* __restrict__ W, int ldw,
    float* __restrict__ C, int ldc, int K)
{
    __shared__ float As[GBK][GBM + 4];
    __shared__ float Bs[GBK][GBN + 4];
    const int m0 = blockIdx.x * GBM;
    const int n0 = blockIdx.y * GBN;
    const int tid = threadIdx.x;
    const int tx = tid & 15, ty = tid >> 4;

    float acc[8][8];
#pragma unroll
    for (int i = 0; i < 8; ++i)
#pragma unroll
        for (int j = 0; j < 8; ++j) acc[i][j] = 0.f;

    for (int k0 = 0; k0 < K; k0 += GBK) {
#pragma unroll
        for (int i = 0; i < 2; ++i) {
            int f4 = tid + i * 256;
            int r = f4 >> 2, c4 = (f4 & 3) << 2;
            float4 av = *(const float4*)&A[(size_t)(m0 + r) * lda + k0 + c4];
            As[c4 + 0][r] = av.x; As[c4 + 1][r] = av.y;
            As[c4 + 2][r] = av.z; As[c4 + 3][r] = av.w;
        }
#pragma unroll
        for (int i = 0; i < 2; ++i) {
            int f4 = tid + i * 256;
            int kk = f4 >> 5, c4 = (f4 & 31) << 2;
            *(float4*)&Bs[kk][c4] = *(const float4*)&W[(size_t)(k0 + kk) * ldw + n0 + c4];
        }
        __syncthreads();
#pragma unroll
        for (int kk = 0; kk < GBK; ++kk) {
            float a[8], b[8];
            float4 t;
            t = *(const float4*)&As[kk][ty * 4];      a[0]=t.x; a[1]=t.y; a[2]=t.z; a[3]=t.w;
            t = *(const float4*)&As[kk][64 + ty * 4]; a[4]=t.x; a[5]=t.y; a[6]=t.z; a[7]=t.w;
            t = *(const float4*)&Bs[kk][tx * 4];      b[0]=t.x; b[1]=t.y; b[2]=t.z; b[3]=t.w;
            t = *(const float4*)&Bs[kk][64 + tx * 4]; b[4]=t.x; b[5]=t.y; b[6]=t.z; b[7]=t.w;
#pragma unroll
            for (int i = 0; i < 8; ++i)
#pragma unroll
                for (int j = 0; j < 8; ++j)
                    acc[i][j] = fmaf(a[i], b[j], acc[i][j]);
        }
        __syncthreads();
    }
#pragma unroll
    for (int i = 0; i < 8; ++i) {
        int r = (i < 4) ? (ty * 4 + i) : (64 + ty * 4 + (i - 4));
        size_t base = (size_t)(m0 + r) * ldc + n0;
#pragma unroll
        for (int jh = 0; jh < 2; ++jh) {
            int c = jh * 64 + tx * 4;
            float4 o;
            o.x = acc[i][jh * 4 + 0]; o.y = acc[i][jh * 4 + 1];
            o.z = acc[i][jh * 4 + 2]; o.w = acc[i][jh * 4 + 3];
            *(float4*)&C[base + c] = o;
        }
    }
}

// ---------------------------------------------------------------------------
// q[m][n] += attr[m][0..3] . Wq[256..259][n]  +  sum_kc qcpart[kc][b][n]
// ---------------------------------------------------------------------------
__global__ __launch_bounds__(256) void qfix_kernel(
    const float* __restrict__ attr, const float* __restrict__ Wq,
    const float* __restrict__ qcpart, float* __restrict__ q)
{
    const int idx = blockIdx.x * 256 + threadIdx.x;
    const int n = idx & 255;
    const int m = idx >> 8;
    const int b = m / P_;
    float a0 = attr[(size_t)m * 4 + 0];
    float a1 = attr[(size_t)m * 4 + 1];
    float a2 = attr[(size_t)m * 4 + 2];
    float a3 = attr[(size_t)m * 4 + 3];
    float add = 0.f;
#pragma unroll
    for (int kc = 0; kc < 4; ++kc)
        add += qcpart[((size_t)kc * 64 + b) * EMB_ + n];
    add = fmaf(a0, Wq[(size_t)256 * EMB_ + n], add);
    add = fmaf(a1, Wq[(size_t)257 * EMB_ + n], add);
    add = fmaf(a2, Wq[(size_t)258 * EMB_ + n], add);
    add = fmaf(a3, Wq[(size_t)259 * EMB_ + n], add);
    q[idx] += add;
}

// ---------------------------------------------------------------------------
// MFMA flash attention. Grid 448 blocks x 1024 threads (16 waves).
// Block = one (b, mtile); wave = head h. All 16 waves read the SAME mask
// rows (L1 broadcast) and tile full K/V rows across heads. XCD-bijective
// mapping puts all 7 mtile-blocks of one b on one XCD (K/V fetched once/L2).
// ---------------------------------------------------------------------------
struct AttnState { float m, l; f32x4 acc; };

template<bool TAIL>
__device__ __forceinline__ void attn_chunk(
    int n0, const bf16_t* __restrict__ kb, const bf16_t* __restrict__ vb,
    const float* __restrict__ maskrow, bf16x8 qfrag, int lr, int lg,
    AttnState& st)
{
    // K A-frag: row n = n0+lr, k(d) = 8*(lg&1)+i ; zero for lg>=2
    int nk = n0 + lr;
    if (TAIL) nk = (nk < N_) ? nk : (N_ - 1);
    bf16x8 ak = *(const bf16x8*)(kb + (size_t)nk * 256 + (lg & 1) * 8);
    if (lg >= 2) ak = (bf16x8)(bf16_t)0.0f;

    f32x4 sc = __builtin_amdgcn_mfma_f32_16x16x32_bf16(ak, qfrag, (f32x4)0.f, 0, 0, 0);

    // scores + mask (lane's 4 keys n = n0+4*lg+r, query p = lr)
    int nm = n0 + 4 * lg;
    if (TAIL) nm = (nm < 996) ? nm : 996;
    float4 mk = *(const float4*)&maskrow[nm];
    float s0 = fmaf(sc[0], 0.25f, mk.x);
    float s1 = fmaf(sc[1], 0.25f, mk.y);
    float s2 = fmaf(sc[2], 0.25f, mk.z);
    float s3 = fmaf(sc[3], 0.25f, mk.w);
    if (TAIL) {
        if (n0 + 4 * lg + 0 >= N_) s0 = -3.0e38f;
        if (n0 + 4 * lg + 1 >= N_) s1 = -3.0e38f;
        if (n0 + 4 * lg + 2 >= N_) s2 = -3.0e38f;
        if (n0 + 4 * lg + 3 >= N_) s3 = -3.0e38f;
    }

    // row max across the 4 lanes sharing lr
    float tmax = fmaxf(fmaxf(s0, s1), fmaxf(s2, s3));
    tmax = fmaxf(tmax, __shfl_xor(tmax, 16));
    tmax = fmaxf(tmax, __shfl_xor(tmax, 32));
    float mn = fmaxf(st.m, tmax);
    if (__any(mn > st.m)) {
        // VALU read of asm-mfma-written acc: cover MFMA->VALU hazard
        asm volatile("s_nop 7\n\ts_nop 3");
        float f = EXP2F((st.m - mn) * L2E);   // first chunk: exp2(-inf)=0
        st.l *= f;
        st.acc *= f;
        st.m = mn;
    }
    float w0 = EXP2F((s0 - st.m) * L2E);
    float w1 = EXP2F((s1 - st.m) * L2E);
    float w2 = EXP2F((s2 - st.m) * L2E);
    float w3 = EXP2F((s3 - st.m) * L2E);
    st.l += (w0 + w1) + (w2 + w3);
    bf16x4 pb;
    pb[0] = (bf16_t)w0; pb[1] = (bf16_t)w1; pb[2] = (bf16_t)w2; pb[3] = (bf16_t)w3;

    // V^T A-frag: row d = lr, k(n) = 4*lg+i  -> V[n0+4lg+i][d=lr]
    bf16x4 av;
#pragma unroll
    for (int i = 0; i < 4; ++i) {
        int nn = n0 + 4 * lg + i;
        if (TAIL) nn = (nn < N_) ? nn : (N_ - 1);   // w=0 kills contribution
        av[i] = vb[(size_t)nn * 256 + lr];
    }
    pv_mfma16(av, pb, st.acc);
}

__global__ __launch_bounds__(1024) void attn_mfma(
    const float* __restrict__ q, const bf16_t* __restrict__ k,
    const bf16_t* __restrict__ v, const float* __restrict__ mask,
    bf16_t* __restrict__ abuf)
{
    // XCD-bijective block mapping: 448 = 8 xcd * 56 slots; 56 = 8 b-groups * 7
    const int x = blockIdx.x;
    const int xcd = x & 7;
    const int slot = x >> 3;                 // 0..55
    const int b = xcd + 8 * (slot / 7);
    const int mtile = slot % 7;
    const int h = threadIdx.x >> 6;          // wave = head
    const int lane = threadIdx.x & 63;
    const int p0 = mtile * 16;
    const int lr = lane & 15;
    const int lg = lane >> 4;

    // Q B-frag (x32): col p = lr, k(d) = 8*lg+i ; zero for lg>=2
    const int pq = (p0 + lr < P_) ? (p0 + lr) : (P_ - 1);
    bf16x8 qfrag = (bf16x8)(bf16_t)0.0f;
    if (lg < 2) {
        const float* qp = q + ((size_t)b * P_ + pq) * 256 + h * 16 + lg * 8;
        float4 q0 = *(const float4*)qp;
        float4 q1 = *(const float4*)(qp + 4);
        qfrag[0] = (bf16_t)q0.x; qfrag[1] = (bf16_t)q0.y;
        qfrag[2] = (bf16_t)q0.z; qfrag[3] = (bf16_t)q0.w;
        qfrag[4] = (bf16_t)q1.x; qfrag[5] = (bf16_t)q1.y;
        qfrag[6] = (bf16_t)q1.z; qfrag[7] = (bf16_t)q1.w;
    }

    const bf16_t* kb = k + ((size_t)b * N_) * 256 + h * 16;
    const bf16_t* vb = v + ((size_t)b * N_) * 256 + h * 16;
    const float* maskrow = mask + ((size_t)b * P_ + pq) * N_;

    AttnState st;
    st.m = -INFINITY;
    st.l = 0.f;
    st.acc = (f32x4)0.f;

    for (int n0 = 0; n0 < 992; n0 += 16)
        attn_chunk<false>(n0, kb, vb, maskrow, qfrag, lr, lg, st);
    attn_chunk<true>(992, kb, vb, maskrow, qfrag, lr, lg, st);

    // row sum of l across the 4 lanes sharing lr
    float L = st.l + __shfl_xor(st.l, 16);
    L += __shfl_xor(L, 32);

    if (p0 + lr < P_) {
        asm volatile("s_nop 7\n\ts_nop 3");   // MFMA->VALU read of acc
        float inv = 1.0f / L;
        bf16x4 o;
        o[0] = (bf16_t)(st.acc[0] * inv);
        o[1] = (bf16_t)(st.acc[1] * inv);
        o[2] = (bf16_t)(st.acc[2] * inv);
        o[3] = (bf16_t)(st.acc[3] * inv);
        // out^T: lane holds out[p=lr][d=4*lg+r]
        *(bf16x4*)(abuf + ((size_t)b * P_ + p0 + lr) * 256 + h * 16 + 4 * lg) = o;
    }
}

// ---------------------------------------------------------------------------
// Pointer logits via MFMA. Grid 1024 blocks x 256 threads (4 waves).
// Block = one (b, 64-key n-group); all 4 waves share the B-frags (L1),
// each wave computes 2 mtiles (8 slots, mtile 7 discarded at epilogue).
// XCD-bijective: the 16 ngrp-blocks of one b land on one XCD.
// ---------------------------------------------------------------------------
__global__ __launch_bounds__(256) void logits_mfma(
    const bf16_t* __restrict__ mh, const bf16_t* __restrict__ nodes,
    const float* __restrict__ mask, float* __restrict__ out)
{
    // 1024 = 8 xcd * 128 slots; 128 = 8 b-groups * 16 ngrps
    const int x = blockIdx.x;
    const int xcd = x & 7;
    const int slot = x >> 3;                  // 0..127
    const int b = xcd + 8 * (slot >> 4);
    const int ngrp = slot & 15;
    const int wave = threadIdx.x >> 6;
    const int lane = threadIdx.x & 63;
    const int n0 = ngrp * 64;
    const int lr = lane & 15;
    const int lk = (lane >> 4) * 8;

    const bf16_t* bbase = nodes + (size_t)b * N_ * 256;
    int nrow[4];
#pragma unroll
    for (int j = 0; j < 4; ++j) {
        int n = n0 + j * 16 + lr;
        nrow[j] = (n < N_) ? n : (N_ - 1);
    }

    // two mtiles per wave: mt = wave + 4*t (t=0,1); mt==7 discarded.
    // mh rows beyond P_ (up to 127) are safe: mhbuf overlay has slack.
    const bf16_t* ap0 = mh + ((size_t)(b * P_) + (wave + 0) * 16 + lr) * 256 + lk;
    const bf16_t* ap1 = mh + ((size_t)(b * P_) + (wave + 4) * 16 + lr) * 256 + lk;

    f32x4 acc0[4], acc1[4];
#pragma unroll
    for (int j = 0; j < 4; ++j) { acc0[j] = (f32x4)0.f; acc1[j] = (f32x4)0.f; }

#pragma unroll 2
    for (int k0 = 0; k0 < 256; k0 += 32) {
        bf16x8 a0 = *(const bf16x8*)(ap0 + k0);
        bf16x8 a1 = *(const bf16x8*)(ap1 + k0);
#pragma unroll
        for (int j = 0; j < 4; ++j) {
            bf16x8 bfr = *(const bf16x8*)(bbase + (size_t)nrow[j] * 256 + lk + k0);
            acc0[j] = __builtin_amdgcn_mfma_f32_16x16x32_bf16(a0, bfr, acc0[j], 0, 0, 0);
            acc1[j] = __builtin_amdgcn_mfma_f32_16x16x32_bf16(a1, bfr, acc1[j], 0, 0, 0);
        }
    }

#pragma unroll
    for (int t = 0; t < 2; ++t) {
        const int mt = wave + 4 * t;
        if (mt >= 7) continue;                 // wave-uniform
        const int prow = mt * 16 + (lane >> 4) * 4;
        f32x4* acc = t ? acc1 : acc0;
#pragma unroll
        for (int j = 0; j < 4; ++j) {
            const int n = n0 + j * 16 + lr;
            if (n >= N_) continue;
#pragma unroll
            for (int r = 0; r < 4; ++r) {
                const int p = prow + r;
                if (p >= P_) continue;
                float xv = acc[j][r] * (1.0f / 16.0f);
                float e = EXP2F(xv * (2.0f * L2E));
                float tt = 1.0f - 2.0f / (e + 1.0f);
                size_t oidx = ((size_t)(b * P_ + p)) * N_ + n;
                out[oidx] = 10.0f * tt + mask[oidx];
            }
        }
    }
}

// ---------------------------------------------------------------------------
// In-place row softmax over N=1000. One block per row, 256 threads.
// ---------------------------------------------------------------------------
__global__ __launch_bounds__(256) void softmax_kernel(float* __restrict__ io)
{
    const size_t row = blockIdx.x;
    float* r = &io[row * N_];
    const int tid = threadIdx.x;
    const int wave = tid >> 6, lane = tid & 63;

    float vals[4];
    float mx = -INFINITY;
#pragma unroll
    for (int j = 0; j < 4; ++j) {
        int n = tid + j * 256;
        vals[j] = (n < N_) ? r[n] : -INFINITY;
        mx = fmaxf(mx, vals[j]);
    }
#pragma unroll
    for (int off = 32; off > 0; off >>= 1) mx = fmaxf(mx, __shfl_down(mx, off));
    __shared__ float redm[4];
    if (lane == 0) redm[wave] = mx;
    __syncthreads();
    mx = fmaxf(fmaxf(redm[0], redm[1]), fmaxf(redm[2], redm[3]));

    float sum = 0.f;
#pragma unroll
    for (int j = 0; j < 4; ++j) {
        float w = EXP2F((vals[j] - mx) * L2E);
        vals[j] = w;
        sum += w;
    }
#pragma unroll
    for (int off = 32; off > 0; off >>= 1) sum += __shfl_down(sum, off);
    __shared__ float reds[4];
    if (lane == 0) reds[wave] = sum;
    __syncthreads();
    sum = reds[0] + reds[1] + reds[2] + reds[3];

    float inv = 1.0f / sum;
#pragma unroll
    for (int j = 0; j < 4; ++j) {
        int n = tid + j * 256;
        if (n < N_) r[n] = vals[j] * inv;
    }
}

// ---------------------------------------------------------------------------
extern "C" void kernel_launch(void* const* d_in, const int* in_sizes, int n_in,
                              void* d_out, int out_size, void* d_ws, size_t ws_size,
                              hipStream_t stream)
{
    const float* lastnode = (const float*)d_in[0];   // [B,P,256]
    const float* attr     = (const float*)d_in[1];   // [B,P,4]
    const float* ctx      = (const float*)d_in[2];   // [B,1024]
    const float* mask     = (const float*)d_in[3];   // [B,P,N]
    const float* nodes    = (const float*)d_in[4];   // [B,N,256]
    const float* Wq       = (const float*)d_in[5];   // [1284,256]
    const float* Wk       = (const float*)d_in[6];   // [256,256]
    const float* Wv       = (const float*)d_in[7];   // [256,256]
    const float* Wcomb    = (const float*)d_in[8];   // [256,256]
    const float* bcomb    = (const float*)d_in[9];   // [256]
    float* out = (float*)d_out;

    // Workspace layout (offsets in floats). Total 27,197,440 f = 108.8 MB.
    float* ws = (float*)d_ws;
    bf16_t* kbuf   = (bf16_t*)(ws);                   // 16,384,000 bf16
    bf16_t* vbuf   = (bf16_t*)(ws + 8192000);         // 16,384,000 bf16
    float*  qbuf   = ws + 16384000;                   // 1,638,400 f
    bf16_t* nbf    = (bf16_t*)(ws + 18022400);        // 16,384,000 bf16
    bf16_t* WkT    = (bf16_t*)(ws + 26214400);        // 65,536 bf16
    bf16_t* WvT    = (bf16_t*)(ws + 26247168);        // 65,536 bf16
    bf16_t* WcombT = (bf16_t*)(ws + 26279936);        // 65,536 bf16
    float*  qcpart = ws + 26312704;                   // 65,536 f (4x64x256)
    bf16_t* abuf   = (bf16_t*)(ws + 26378240);        // 1,638,400 bf16
    // Overlay: mhbuf reuses kbuf (K dead after attn_mfma); logits reads rows
    // up to b*100+127 -> slack is inside kbuf's 16.4M elements (finite stale K).
    bf16_t* mhbuf = kbuf;

    // 1) nodes -> bf16 (also the logits B operand)
    cvt_bf16_kernel<<<16000, 256, 0, stream>>>(nodes, nbf, 4096000);

    // 2) weight transposes -> bf16
    wtrans_kernel<<<dim3(8, 8, 3), 256, 0, stream>>>(Wk, Wv, Wcomb, WkT, WvT, WcombT);

    // 3) q pipeline (f32)
    qc_kernel<<<dim3(64, 4), 256, 0, stream>>>(ctx, Wq, qcpart);
    gemm128<<<dim3(50, 2), 256, 0, stream>>>(lastnode, 256, Wq, 256, qbuf, 256, 256);
    qfix_kernel<<<6400, 256, 0, stream>>>(attr, Wq, qcpart, qbuf);

    // 4) k, v projections (MFMA, bf16 out)
    mfma_gemm<false, true><<<4000, 256, 0, stream>>>(nbf, WkT, nullptr, kbuf);
    mfma_gemm<false, true><<<4000, 256, 0, stream>>>(nbf, WvT, nullptr, vbuf);

    // 5) fused MFMA flash attention -> abuf (bf16)
    attn_mfma<<<448, 1024, 0, stream>>>(qbuf, kbuf, vbuf, mask, abuf);

    // 6) combine projection (MFMA, bias, bf16 out into mhbuf)
    mfma_gemm<true, true><<<400, 256, 0, stream>>>(abuf, WcombT, bcomb, mhbuf);

    // 7) pointer logits (MFMA) + softmax
    logits_mfma<<<1024, 256, 0, stream>>>(mhbuf, nbf, mask, out);
    softmax_kernel<<<B_ * P_, 256, 0, stream>>>(out);
}

// Round 6
// 341.894 us; speedup vs baseline: 2.3845x; 1.1088x over previous
//
#include <hip/hip_runtime.h>
#include <hip/hip_bf16.h>
#include <math.h>

// Problem constants (from reference)
#define B_  64
#define P_  100
#define N_  1000
#define EMB_ 256
#define H_  16
#define D_  16
#define CTX_ 1024
#define L2E 1.44269504088896340736f

#if __has_builtin(__builtin_amdgcn_exp2f)
#define EXP2F(x) __builtin_amdgcn_exp2f(x)
#else
#define EXP2F(x) exp2f(x)
#endif

typedef __bf16 bf16_t;
typedef bf16_t bf16x8 __attribute__((ext_vector_type(8)));
typedef bf16_t bf16x4 __attribute__((ext_vector_type(4)));
typedef float  f32x4  __attribute__((ext_vector_type(4)));

// v_mfma_f32_16x16x16_bf16 via inline asm (no builtin assumed on gfx950).
// s_nop 1 covers VALU-write -> MFMA-read (2 states). Callers place >=11
// wait states before VALU reads of c (s_nop 7+3 in rescale/merge/epilogue).
__device__ __forceinline__ void pv_mfma16(bf16x4 a, bf16x4 b, f32x4& c)
{
    asm volatile("s_nop 1\n\tv_mfma_f32_16x16x16_bf16 %0, %1, %2, %0"
                 : "+v"(c) : "v"(a), "v"(b));
}

// ---------------------------------------------------------------------------
// f32 -> bf16 bulk convert (4 elems/thread)
// ---------------------------------------------------------------------------
__global__ __launch_bounds__(256) void cvt_bf16_kernel(
    const float* __restrict__ in, bf16_t* __restrict__ out, int n4)
{
    int i = blockIdx.x * 256 + threadIdx.x;
    if (i >= n4) return;
    float4 v = ((const float4*)in)[i];
    bf16x4 o;
    o[0] = (bf16_t)v.x; o[1] = (bf16_t)v.y; o[2] = (bf16_t)v.z; o[3] = (bf16_t)v.w;
    ((bf16x4*)out)[i] = o;
}

// ---------------------------------------------------------------------------
// Transpose four 256x256 f32 weights -> bf16 WT[n][k]
// ---------------------------------------------------------------------------
__global__ __launch_bounds__(256) void wtrans_kernel(
    const float* __restrict__ W0, const float* __restrict__ W1,
    const float* __restrict__ W2, const float* __restrict__ W3,
    bf16_t* __restrict__ T0, bf16_t* __restrict__ T1,
    bf16_t* __restrict__ T2, bf16_t* __restrict__ T3)
{
    __shared__ float t[32][33];
    const float* W = (blockIdx.z == 0) ? W0 : (blockIdx.z == 1) ? W1
                   : (blockIdx.z == 2) ? W2 : W3;
    bf16_t*      T = (blockIdx.z == 0) ? T0 : (blockIdx.z == 1) ? T1
                   : (blockIdx.z == 2) ? T2 : T3;
    const int n0 = blockIdx.x * 32, k0 = blockIdx.y * 32;
    const int tx = threadIdx.x & 31, ty = threadIdx.x >> 5;   // ty 0..7
#pragma unroll
    for (int i = 0; i < 4; ++i)
        t[ty + i * 8][tx] = W[(size_t)(k0 + ty + i * 8) * 256 + n0 + tx];
    __syncthreads();
#pragma unroll
    for (int i = 0; i < 4; ++i)
        T[(size_t)(n0 + ty + i * 8) * 256 + k0 + tx] = (bf16_t)t[tx][ty + i * 8];
}

// ---------------------------------------------------------------------------
// MFMA GEMM: C[M,256] = A[M,256] @ BT[256,256]^T, A/BT bf16 row-major.
// Block = 4 waves; wave w computes rows m0..m0+15, cols w*64..w*64+63.
// grid.x = M/16. No LDS. Optional bias, optional bf16 output.
// ---------------------------------------------------------------------------
template<bool BIAS, bool OUT_BF16>
__global__ __launch_bounds__(256) void mfma_gemm(
    const bf16_t* __restrict__ A, const bf16_t* __restrict__ BT,
    const float* __restrict__ bias, void* __restrict__ Cout)
{
    const int wave = threadIdx.x >> 6;
    const int lane = threadIdx.x & 63;
    const int m0 = blockIdx.x * 16;
    const int n0 = wave * 64;
    const int lr = lane & 15;
    const int lk = (lane >> 4) * 8;

    const bf16_t* ap = A  + (size_t)(m0 + lr) * 256 + lk;
    const bf16_t* bp = BT + (size_t)(n0 + lr) * 256 + lk;

    f32x4 acc[4];
#pragma unroll
    for (int j = 0; j < 4; ++j) acc[j] = (f32x4)0.f;

#pragma unroll 2
    for (int k0 = 0; k0 < 256; k0 += 32) {
        bf16x8 a = *(const bf16x8*)(ap + k0);
#pragma unroll
        for (int j = 0; j < 4; ++j) {
            bf16x8 b = *(const bf16x8*)(bp + (size_t)j * 16 * 256 + k0);
            acc[j] = __builtin_amdgcn_mfma_f32_16x16x32_bf16(a, b, acc[j], 0, 0, 0);
        }
    }

    const int crow = m0 + (lane >> 4) * 4;
#pragma unroll
    for (int j = 0; j < 4; ++j) {
        const int col = n0 + j * 16 + lr;
        const float bv = BIAS ? bias[col] : 0.f;
#pragma unroll
        for (int r = 0; r < 4; ++r) {
            float val = acc[j][r] + bv;
            if (OUT_BF16)
                ((bf16_t*)Cout)[(size_t)(crow + r) * 256 + col] = (bf16_t)val;
            else
                ((float*)Cout)[(size_t)(crow + r) * 256 + col] = val;
        }
    }
}

// ---------------------------------------------------------------------------
// Fused K+V projection: reads A once, two B operands, two bf16 outputs.
// ---------------------------------------------------------------------------
__global__ __launch_bounds__(256) void mfma_gemm_kv(
    const bf16_t* __restrict__ A, const bf16_t* __restrict__ BTk,
    const bf16_t* __restrict__ BTv,
    bf16_t* __restrict__ Ck, bf16_t* __restrict__ Cv)
{
    const int wave = threadIdx.x >> 6;
    const int lane = threadIdx.x & 63;
    const int m0 = blockIdx.x * 16;
    const int n0 = wave * 64;
    const int lr = lane & 15;
    const int lk = (lane >> 4) * 8;

    const bf16_t* ap  = A   + (size_t)(m0 + lr) * 256 + lk;
    const bf16_t* bpk = BTk + (size_t)(n0 + lr) * 256 + lk;
    const bf16_t* bpv = BTv + (size_t)(n0 + lr) * 256 + lk;

    f32x4 acck[4], accv[4];
#pragma unroll
    for (int j = 0; j < 4; ++j) { acck[j] = (f32x4)0.f; accv[j] = (f32x4)0.f; }

#pragma unroll 2
    for (int k0 = 0; k0 < 256; k0 += 32) {
        bf16x8 a = *(const bf16x8*)(ap + k0);
#pragma unroll
        for (int j = 0; j < 4; ++j) {
            bf16x8 bk = *(const bf16x8*)(bpk + (size_t)j * 16 * 256 + k0);
            bf16x8 bv = *(const bf16x8*)(bpv + (size_t)j * 16 * 256 + k0);
            acck[j] = __builtin_amdgcn_mfma_f32_16x16x32_bf16(a, bk, acck[j], 0, 0, 0);
            accv[j] = __builtin_amdgcn_mfma_f32_16x16x32_bf16(a, bv, accv[j], 0, 0, 0);
        }
    }

    const int crow = m0 + (lane >> 4) * 4;
#pragma unroll
    for (int j = 0; j < 4; ++j) {
        const int col = n0 + j * 16 + lr;
#pragma unroll
        for (int r = 0; r < 4; ++r) {
            Ck[(size_t)(crow + r) * 256 + col] = (bf16_t)acck[j][r];
            Cv[(size_t)(crow + r) * 256 + col] = (bf16_t)accv[j][r];
        }
    }
}

// ---------------------------------------------------------------------------
// qc partials: qcpart[kc][b][n] = sum_{k in chunk kc} ctx[b][k]*Wq[260+k][n]
// grid (64, 4). ctx element is wave-uniform -> scalar loads.
// ---------------------------------------------------------------------------
__global__ __launch_bounds__(256) void qc_kernel(
    const float* __restrict__ ctx, const float* __restrict__ Wq,
    float* __restrict__ qcpart)
{
    const int b = blockIdx.x;
    const int kc = blockIdx.y;
    const int tid = threadIdx.x;
    const float* c = ctx + (size_t)b * CTX_ + kc * 256;
    const float* w = Wq + (size_t)(260 + kc * 256) * EMB_ + tid;
    float acc = 0.f;
#pragma unroll 8
    for (int kk = 0; kk < 256; ++kk)
        acc = fmaf(c[kk], w[(size_t)kk * EMB_], acc);
    qcpart[((size_t)kc * 64 + b) * EMB_ + tid] = acc;
}

// ---------------------------------------------------------------------------
// q[m][n] += attr[m][0..3] . Wq[256..259][n]  +  sum_kc qcpart[kc][b][n]
// ---------------------------------------------------------------------------
__global__ __launch_bounds__(256) void qfix_kernel(
    const float* __restrict__ attr, const float* __restrict__ Wq,
    const float* __restrict__ qcpart, float* __restrict__ q)
{
    const int idx = blockIdx.x * 256 + threadIdx.x;
    const int n = idx & 255;
    const int m = idx >> 8;
    const int b = m / P_;
    float a0 = attr[(size_t)m * 4 + 0];
    float a1 = attr[(size_t)m * 4 + 1];
    float a2 = attr[(size_t)m * 4 + 2];
    float a3 = attr[(size_t)m * 4 + 3];
    float add = 0.f;
#pragma unroll
    for (int kc = 0; kc < 4; ++kc)
        add += qcpart[((size_t)kc * 64 + b) * EMB_ + n];
    add = fmaf(a0, Wq[(size_t)256 * EMB_ + n], add);
    add = fmaf(a1, Wq[(size_t)257 * EMB_ + n], add);
    add = fmaf(a2, Wq[(size_t)258 * EMB_ + n], add);
    add = fmaf(a3, Wq[(size_t)259 * EMB_ + n], add);
    q[idx] += add;
}

// ---------------------------------------------------------------------------
// MFMA flash attention. Grid 448 x 1024 (16 waves = 16 heads per (b,mtile)).
// v5: defer-max (THR=8) removes cross-lane shfls from the common path;
// two interleaved accumulation states (even/odd chunks) double ILP.
// XCD-bijective block mapping keeps one b's blocks on one XCD L2.
// ---------------------------------------------------------------------------
struct AttnState { float m, l; f32x4 acc; };

template<bool TAIL>
__device__ __forceinline__ void attn_chunk(
    int n0, const bf16_t* __restrict__ kb, const bf16_t* __restrict__ vb,
    const float* __restrict__ maskrow, bf16x8 qfrag, int lr, int lg,
    AttnState& st)
{
    // K A-frag: row n = n0+lr, k(d) = 8*(lg&1)+i ; zero for lg>=2
    int nk = n0 + lr;
    if (TAIL) nk = (nk < N_) ? nk : (N_ - 1);
    bf16x8 ak = *(const bf16x8*)(kb + (size_t)nk * 256 + (lg & 1) * 8);
    if (lg >= 2) ak = (bf16x8)(bf16_t)0.0f;

    f32x4 sc = __builtin_amdgcn_mfma_f32_16x16x32_bf16(ak, qfrag, (f32x4)0.f, 0, 0, 0);

    // scores + mask (lane's 4 keys n = n0+4*lg+r, query p = lr)
    int nm = n0 + 4 * lg;
    if (TAIL) nm = (nm < 996) ? nm : 996;
    float4 mk = *(const float4*)&maskrow[nm];
    float s0 = fmaf(sc[0], 0.25f, mk.x);
    float s1 = fmaf(sc[1], 0.25f, mk.y);
    float s2 = fmaf(sc[2], 0.25f, mk.z);
    float s3 = fmaf(sc[3], 0.25f, mk.w);
    if (TAIL) {
        if (n0 + 4 * lg + 0 >= N_) s0 = -3.0e38f;
        if (n0 + 4 * lg + 1 >= N_) s1 = -3.0e38f;
        if (n0 + 4 * lg + 2 >= N_) s2 = -3.0e38f;
        if (n0 + 4 * lg + 3 >= N_) s3 = -3.0e38f;
    }

    // defer-max: common path is per-lane only (no cross-lane ops)
    float tmax = fmaxf(fmaxf(s0, s1), fmaxf(s2, s3));
    if (__any(tmax > st.m + 8.0f)) {        // rare (~once per state)
        float rmax = fmaxf(tmax, __shfl_xor(tmax, 16));
        rmax = fmaxf(rmax, __shfl_xor(rmax, 32));
        float mn = fmaxf(st.m, rmax);
        asm volatile("s_nop 7\n\ts_nop 3"); // MFMA->VALU read of st.acc
        float f = EXP2F((st.m - mn) * L2E); // first time: exp2(-inf)=0
        st.l *= f;
        st.acc *= f;
        st.m = mn;
    }
    float w0 = EXP2F((s0 - st.m) * L2E);    // bounded by e^8
    float w1 = EXP2F((s1 - st.m) * L2E);
    float w2 = EXP2F((s2 - st.m) * L2E);
    float w3 = EXP2F((s3 - st.m) * L2E);
    st.l += (w0 + w1) + (w2 + w3);
    bf16x4 pb;
    pb[0] = (bf16_t)w0; pb[1] = (bf16_t)w1; pb[2] = (bf16_t)w2; pb[3] = (bf16_t)w3;

    // V^T A-frag: row d = lr, k(n) = 4*lg+i  -> V[n0+4lg+i][d=lr]
    bf16x4 av;
#pragma unroll
    for (int i = 0; i < 4; ++i) {
        int nn = n0 + 4 * lg + i;
        if (TAIL) nn = (nn < N_) ? nn : (N_ - 1);   // w=0 kills contribution
        av[i] = vb[(size_t)nn * 256 + lr];
    }
    pv_mfma16(av, pb, st.acc);
}

__global__ __launch_bounds__(1024) void attn_mfma(
    const float* __restrict__ q, const bf16_t* __restrict__ k,
    const bf16_t* __restrict__ v, const float* __restrict__ mask,
    bf16_t* __restrict__ abuf)
{
    // XCD-bijective block mapping: 448 = 8 xcd * 56 slots; 56 = 8 b-groups * 7
    const int x = blockIdx.x;
    const int xcd = x & 7;
    const int slot = x >> 3;                 // 0..55
    const int b = xcd + 8 * (slot / 7);
    const int mtile = slot % 7;
    const int h = threadIdx.x >> 6;          // wave = head
    const int lane = threadIdx.x & 63;
    const int p0 = mtile * 16;
    const int lr = lane & 15;
    const int lg = lane >> 4;

    // Q B-frag (x32): col p = lr, k(d) = 8*lg+i ; zero for lg>=2
    const int pq = (p0 + lr < P_) ? (p0 + lr) : (P_ - 1);
    bf16x8 qfrag = (bf16x8)(bf16_t)0.0f;
    if (lg < 2) {
        const float* qp = q + ((size_t)b * P_ + pq) * 256 + h * 16 + lg * 8;
        float4 q0 = *(const float4*)qp;
        float4 q1 = *(const float4*)(qp + 4);
        qfrag[0] = (bf16_t)q0.x; qfrag[1] = (bf16_t)q0.y;
        qfrag[2] = (bf16_t)q0.z; qfrag[3] = (bf16_t)q0.w;
        qfrag[4] = (bf16_t)q1.x; qfrag[5] = (bf16_t)q1.y;
        qfrag[6] = (bf16_t)q1.z; qfrag[7] = (bf16_t)q1.w;
    }

    const bf16_t* kb = k + ((size_t)b * N_) * 256 + h * 16;
    const bf16_t* vb = v + ((size_t)b * N_) * 256 + h * 16;
    const float* maskrow = mask + ((size_t)b * P_ + pq) * N_;

    AttnState stA, stB;
    stA.m = -INFINITY; stA.l = 0.f; stA.acc = (f32x4)0.f;
    stB.m = -INFINITY; stB.l = 0.f; stB.acc = (f32x4)0.f;

    // 63 chunks: 30 pairs + chunks 960(A), 976(B), 992(A,tail)
    for (int n0 = 0; n0 < 960; n0 += 32) {
        attn_chunk<false>(n0,      kb, vb, maskrow, qfrag, lr, lg, stA);
        attn_chunk<false>(n0 + 16, kb, vb, maskrow, qfrag, lr, lg, stB);
    }
    attn_chunk<false>(960, kb, vb, maskrow, qfrag, lr, lg, stA);
    attn_chunk<false>(976, kb, vb, maskrow, qfrag, lr, lg, stB);
    attn_chunk<true>(992, kb, vb, maskrow, qfrag, lr, lg, stA);

    // merge the two states (flash combine)
    asm volatile("s_nop 7\n\ts_nop 3");       // MFMA->VALU read of accs
    float mn = fmaxf(stA.m, stB.m);
    float fA = EXP2F((stA.m - mn) * L2E);
    float fB = EXP2F((stB.m - mn) * L2E);
    float l = stA.l * fA + stB.l * fB;
    f32x4 acc = stA.acc * fA + stB.acc * fB;

    // row sum of l across the 4 lanes sharing lr
    float L = l + __shfl_xor(l, 16);
    L += __shfl_xor(L, 32);

    if (p0 + lr < P_) {
        float inv = 1.0f / L;
        bf16x4 o;
        o[0] = (bf16_t)(acc[0] * inv);
        o[1] = (bf16_t)(acc[1] * inv);
        o[2] = (bf16_t)(acc[2] * inv);
        o[3] = (bf16_t)(acc[3] * inv);
        // out^T: lane holds out[p=lr][d=4*lg+r]
        *(bf16x4*)(abuf + ((size_t)b * P_ + p0 + lr) * 256 + h * 16 + 4 * lg) = o;
    }
}

// ---------------------------------------------------------------------------
// Pointer logits via MFMA. Grid 1024 blocks x 256 threads (4 waves).
// Block = one (b, 64-key n-group); all 4 waves share the B-frags (L1),
// each wave computes 2 mtiles (8 slots, mtile 7 discarded at epilogue).
// XCD-bijective: the 16 ngrp-blocks of one b land on one XCD.
// ---------------------------------------------------------------------------
__global__ __launch_bounds__(256) void logits_mfma(
    const bf16_t* __restrict__ mh, const bf16_t* __restrict__ nodes,
    const float* __restrict__ mask, float* __restrict__ out)
{
    // 1024 = 8 xcd * 128 slots; 128 = 8 b-groups * 16 ngrps
    const int x = blockIdx.x;
    const int xcd = x & 7;
    const int slot = x >> 3;                  // 0..127
    const int b = xcd + 8 * (slot >> 4);
    const int ngrp = slot & 15;
    const int wave = threadIdx.x >> 6;
    const int lane = threadIdx.x & 63;
    const int n0 = ngrp * 64;
    const int lr = lane & 15;
    const int lk = (lane >> 4) * 8;

    const bf16_t* bbase = nodes + (size_t)b * N_ * 256;
    int nrow[4];
#pragma unroll
    for (int j = 0; j < 4; ++j) {
        int n = n0 + j * 16 + lr;
        nrow[j] = (n < N_) ? n : (N_ - 1);
    }

    // two mtiles per wave: mt = wave + 4*t (t=0,1); mt==7 discarded.
    // mh rows beyond P_ (up to 127) are safe: mhbuf overlay has slack.
    const bf16_t* ap0 = mh + ((size_t)(b * P_) + (wave + 0) * 16 + lr) * 256 + lk;
    const bf16_t* ap1 = mh + ((size_t)(b * P_) + (wave + 4) * 16 + lr) * 256 + lk;

    f32x4 acc0[4], acc1[4];
#pragma unroll
    for (int j = 0; j < 4; ++j) { acc0[j] = (f32x4)0.f; acc1[j] = (f32x4)0.f; }

#pragma unroll 2
    for (int k0 = 0; k0 < 256; k0 += 32) {
        bf16x8 a0 = *(const bf16x8*)(ap0 + k0);
        bf16x8 a1 = *(const bf16x8*)(ap1 + k0);
#pragma unroll
        for (int j = 0; j < 4; ++j) {
            bf16x8 bfr = *(const bf16x8*)(bbase + (size_t)nrow[j] * 256 + lk + k0);
            acc0[j] = __builtin_amdgcn_mfma_f32_16x16x32_bf16(a0, bfr, acc0[j], 0, 0, 0);
            acc1[j] = __builtin_amdgcn_mfma_f32_16x16x32_bf16(a1, bfr, acc1[j], 0, 0, 0);
        }
    }

#pragma unroll
    for (int t = 0; t < 2; ++t) {
        const int mt = wave + 4 * t;
        if (mt >= 7) continue;                 // wave-uniform
        const int prow = mt * 16 + (lane >> 4) * 4;
        f32x4* acc = t ? acc1 : acc0;
#pragma unroll
        for (int j = 0; j < 4; ++j) {
            const int n = n0 + j * 16 + lr;
            if (n >= N_) continue;
#pragma unroll
            for (int r = 0; r < 4; ++r) {
                const int p = prow + r;
                if (p >= P_) continue;
                float xv = acc[j][r] * (1.0f / 16.0f);
                float e = EXP2F(xv * (2.0f * L2E));
                float tt = 1.0f - 2.0f / (e + 1.0f);
                size_t oidx = ((size_t)(b * P_ + p)) * N_ + n;
                out[oidx] = 10.0f * tt + mask[oidx];
            }
        }
    }
}

// ---------------------------------------------------------------------------
// In-place row softmax over N=1000. One block per row, 256 threads.
// ---------------------------------------------------------------------------
__global__ __launch_bounds__(256) void softmax_kernel(float* __restrict__ io)
{
    const size_t row = blockIdx.x;
    float* r = &io[row * N_];
    const int tid = threadIdx.x;
    const int wave = tid >> 6, lane = tid & 63;

    float vals[4];
    float mx = -INFINITY;
#pragma unroll
    for (int j = 0; j < 4; ++j) {
        int n = tid + j * 256;
        vals[j] = (n < N_) ? r[n] : -INFINITY;
        mx = fmaxf(mx, vals[j]);
    }
#pragma unroll
    for (int off = 32; off > 0; off >>= 1) mx = fmaxf(mx, __shfl_down(mx, off));
    __shared__ float redm[4];
    if (lane == 0) redm[wave] = mx;
    __syncthreads();
    mx = fmaxf(fmaxf(redm[0], redm[1]), fmaxf(redm[2], redm[3]));

    float sum = 0.f;
#pragma unroll
    for (int j = 0; j < 4; ++j) {
        float w = EXP2F((vals[j] - mx) * L2E);
        vals[j] = w;
        sum += w;
    }
#pragma unroll
    for (int off = 32; off > 0; off >>= 1) sum += __shfl_down(sum, off);
    __shared__ float reds[4];
    if (lane == 0) reds[wave] = sum;
    __syncthreads();
    sum = reds[0] + reds[1] + reds[2] + reds[3];

    float inv = 1.0f / sum;
#pragma unroll
    for (int j = 0; j < 4; ++j) {
        int n = tid + j * 256;
        if (n < N_) r[n] = vals[j] * inv;
    }
}

// ---------------------------------------------------------------------------
extern "C" void kernel_launch(void* const* d_in, const int* in_sizes, int n_in,
                              void* d_out, int out_size, void* d_ws, size_t ws_size,
                              hipStream_t stream)
{
    const float* lastnode = (const float*)d_in[0];   // [B,P,256]
    const float* attr     = (const float*)d_in[1];   // [B,P,4]
    const float* ctx      = (const float*)d_in[2];   // [B,1024]
    const float* mask     = (const float*)d_in[3];   // [B,P,N]
    const float* nodes    = (const float*)d_in[4];   // [B,N,256]
    const float* Wq       = (const float*)d_in[5];   // [1284,256]
    const float* Wk       = (const float*)d_in[6];   // [256,256]
    const float* Wv       = (const float*)d_in[7];   // [256,256]
    const float* Wcomb    = (const float*)d_in[8];   // [256,256]
    const float* bcomb    = (const float*)d_in[9];   // [256]
    float* out = (float*)d_out;

    // Workspace layout (offsets in floats). Total 28,049,408 f = 112.2 MB.
    float* ws = (float*)d_ws;
    bf16_t* kbuf   = (bf16_t*)(ws);                   // 16,384,000 bf16
    bf16_t* vbuf   = (bf16_t*)(ws + 8192000);         // 16,384,000 bf16
    float*  qbuf   = ws + 16384000;                   // 1,638,400 f
    bf16_t* nbf    = (bf16_t*)(ws + 18022400);        // 16,384,000 bf16
    bf16_t* WkT    = (bf16_t*)(ws + 26214400);        // 65,536 bf16
    bf16_t* WvT    = (bf16_t*)(ws + 26247168);        // 65,536 bf16
    bf16_t* WcombT = (bf16_t*)(ws + 26279936);        // 65,536 bf16
    bf16_t* WqmT   = (bf16_t*)(ws + 26312704);        // 65,536 bf16
    float*  qcpart = ws + 26345472;                   // 65,536 f (4x64x256)
    bf16_t* abuf   = (bf16_t*)(ws + 26411008);        // 1,638,400 bf16
    bf16_t* lnbf   = (bf16_t*)(ws + 27230208);        // 1,638,400 bf16
    // Overlay: mhbuf reuses kbuf (K dead after attn_mfma); logits reads rows
    // up to b*100+127 -> slack is inside kbuf's 16.4M elements.
    bf16_t* mhbuf = kbuf;

    // 1) nodes & lastnode -> bf16
    cvt_bf16_kernel<<<16000, 256, 0, stream>>>(nodes, nbf, 4096000);
    cvt_bf16_kernel<<<1600, 256, 0, stream>>>(lastnode, lnbf, 409600);

    // 2) weight transposes -> bf16 (Wk, Wv, Wcomb, Wq[0:256))
    wtrans_kernel<<<dim3(8, 8, 4), 256, 0, stream>>>(
        Wk, Wv, Wcomb, Wq, WkT, WvT, WcombT, WqmT);

    // 3) q pipeline: main term MFMA (f32 out) + ctx partials + fixup
    qc_kernel<<<dim3(64, 4), 256, 0, stream>>>(ctx, Wq, qcpart);
    mfma_gemm<false, false><<<400, 256, 0, stream>>>(lnbf, WqmT, nullptr, qbuf);
    qfix_kernel<<<6400, 256, 0, stream>>>(attr, Wq, qcpart, qbuf);

    // 4) fused k+v projection (MFMA, bf16 out)
    mfma_gemm_kv<<<4000, 256, 0, stream>>>(nbf, WkT, WvT, kbuf, vbuf);

    // 5) fused MFMA flash attention -> abuf (bf16)
    attn_mfma<<<448, 1024, 0, stream>>>(qbuf, kbuf, vbuf, mask, abuf);

    // 6) combine projection (MFMA, bias, bf16 out into mhbuf)
    mfma_gemm<true, true><<<400, 256, 0, stream>>>(abuf, WcombT, bcomb, mhbuf);

    // 7) pointer logits (MFMA) + softmax
    logits_mfma<<<1024, 256, 0, stream>>>(mhbuf, nbf, mask, out);
    softmax_kernel<<<B_ * P_, 256, 0, stream>>>(out);
}

// Round 7
// 294.743 us; speedup vs baseline: 2.7660x; 1.1600x over previous
//
#include <hip/hip_runtime.h>
#include <hip/hip_bf16.h>
#include <math.h>

// Problem constants (from reference)
#define B_  64
#define P_  100
#define N_  1000
#define EMB_ 256
#define H_  16
#define D_  16
#define CTX_ 1024
#define L2E 1.44269504088896340736f

#if __has_builtin(__builtin_amdgcn_exp2f)
#define EXP2F(x) __builtin_amdgcn_exp2f(x)
#else
#define EXP2F(x) exp2f(x)
#endif

typedef __bf16 bf16_t;
typedef bf16_t bf16x8 __attribute__((ext_vector_type(8)));
typedef bf16_t bf16x4 __attribute__((ext_vector_type(4)));
typedef float  f32x4  __attribute__((ext_vector_type(4)));

// v_mfma_f32_16x16x16_bf16 via inline asm (no builtin assumed on gfx950).
// s_nop 1 covers VALU-write -> MFMA-read (2 states). Callers place >=11
// wait states before VALU reads of c (s_nop 7+3 in rescale/merge/epilogue).
__device__ __forceinline__ void pv_mfma16(bf16x4 a, bf16x4 b, f32x4& c)
{
    asm volatile("s_nop 1\n\tv_mfma_f32_16x16x16_bf16 %0, %1, %2, %0"
                 : "+v"(c) : "v"(a), "v"(b));
}

// ---------------------------------------------------------------------------
// f32 -> bf16 bulk convert (4 elems/thread)
// ---------------------------------------------------------------------------
__global__ __launch_bounds__(256) void cvt_bf16_kernel(
    const float* __restrict__ in, bf16_t* __restrict__ out, int n4)
{
    int i = blockIdx.x * 256 + threadIdx.x;
    if (i >= n4) return;
    float4 v = ((const float4*)in)[i];
    bf16x4 o;
    o[0] = (bf16_t)v.x; o[1] = (bf16_t)v.y; o[2] = (bf16_t)v.z; o[3] = (bf16_t)v.w;
    ((bf16x4*)out)[i] = o;
}

// ---------------------------------------------------------------------------
// Transpose four 256x256 f32 weights -> bf16 WT[n][k]
// ---------------------------------------------------------------------------
__global__ __launch_bounds__(256) void wtrans_kernel(
    const float* __restrict__ W0, const float* __restrict__ W1,
    const float* __restrict__ W2, const float* __restrict__ W3,
    bf16_t* __restrict__ T0, bf16_t* __restrict__ T1,
    bf16_t* __restrict__ T2, bf16_t* __restrict__ T3)
{
    __shared__ float t[32][33];
    const float* W = (blockIdx.z == 0) ? W0 : (blockIdx.z == 1) ? W1
                   : (blockIdx.z == 2) ? W2 : W3;
    bf16_t*      T = (blockIdx.z == 0) ? T0 : (blockIdx.z == 1) ? T1
                   : (blockIdx.z == 2) ? T2 : T3;
    const int n0 = blockIdx.x * 32, k0 = blockIdx.y * 32;
    const int tx = threadIdx.x & 31, ty = threadIdx.x >> 5;   // ty 0..7
#pragma unroll
    for (int i = 0; i < 4; ++i)
        t[ty + i * 8][tx] = W[(size_t)(k0 + ty + i * 8) * 256 + n0 + tx];
    __syncthreads();
#pragma unroll
    for (int i = 0; i < 4; ++i)
        T[(size_t)(n0 + ty + i * 8) * 256 + k0 + tx] = (bf16_t)t[tx][ty + i * 8];
}

// ---------------------------------------------------------------------------
// MFMA GEMM: C[M,256] = A[M,256] @ BT[256,256]^T, A/BT bf16 row-major.
// Block = 4 waves; wave w computes rows m0..m0+15, cols w*64..w*64+63.
// grid.x = M/16. No LDS. Optional bias, optional bf16 output.
// ---------------------------------------------------------------------------
template<bool BIAS, bool OUT_BF16>
__global__ __launch_bounds__(256) void mfma_gemm(
    const bf16_t* __restrict__ A, const bf16_t* __restrict__ BT,
    const float* __restrict__ bias, void* __restrict__ Cout)
{
    const int wave = threadIdx.x >> 6;
    const int lane = threadIdx.x & 63;
    const int m0 = blockIdx.x * 16;
    const int n0 = wave * 64;
    const int lr = lane & 15;
    const int lk = (lane >> 4) * 8;

    const bf16_t* ap = A  + (size_t)(m0 + lr) * 256 + lk;
    const bf16_t* bp = BT + (size_t)(n0 + lr) * 256 + lk;

    f32x4 acc[4];
#pragma unroll
    for (int j = 0; j < 4; ++j) acc[j] = (f32x4)0.f;

#pragma unroll 2
    for (int k0 = 0; k0 < 256; k0 += 32) {
        bf16x8 a = *(const bf16x8*)(ap + k0);
#pragma unroll
        for (int j = 0; j < 4; ++j) {
            bf16x8 b = *(const bf16x8*)(bp + (size_t)j * 16 * 256 + k0);
            acc[j] = __builtin_amdgcn_mfma_f32_16x16x32_bf16(a, b, acc[j], 0, 0, 0);
        }
    }

    const int crow = m0 + (lane >> 4) * 4;
#pragma unroll
    for (int j = 0; j < 4; ++j) {
        const int col = n0 + j * 16 + lr;
        const float bv = BIAS ? bias[col] : 0.f;
#pragma unroll
        for (int r = 0; r < 4; ++r) {
            float val = acc[j][r] + bv;
            if (OUT_BF16)
                ((bf16_t*)Cout)[(size_t)(crow + r) * 256 + col] = (bf16_t)val;
            else
                ((float*)Cout)[(size_t)(crow + r) * 256 + col] = val;
        }
    }
}

// ---------------------------------------------------------------------------
// Fused K+V projection v2 (R6 post-mortem: was latency-bound, 140 us,
// MfmaUtil 4.7%, both pipes idle).
//  - 2 m-tiles per wave: 16 MFMA per 10 loads per k-iter (was 8 per 9).
//  - swapped-operand MFMA: lane holds 4 CONSECUTIVE columns -> bf16x4
//    coalesced stores (was 32 scalar 2B stores).
// Block = 32 rows x 256 cols of BOTH K and V. grid.x = M/32 = 2000.
// ---------------------------------------------------------------------------
__global__ __launch_bounds__(256) void mfma_gemm_kv(
    const bf16_t* __restrict__ A, const bf16_t* __restrict__ BTk,
    const bf16_t* __restrict__ BTv,
    bf16_t* __restrict__ Ck, bf16_t* __restrict__ Cv)
{
    const int wave = threadIdx.x >> 6;
    const int lane = threadIdx.x & 63;
    const int m0 = blockIdx.x * 32;
    const int n0 = wave * 64;
    const int lr = lane & 15;
    const int lk = (lane >> 4) * 8;

    const bf16_t* ap0 = A   + (size_t)(m0 + lr) * 256 + lk;
    const bf16_t* ap1 = A   + (size_t)(m0 + 16 + lr) * 256 + lk;
    const bf16_t* bpk = BTk + (size_t)(n0 + lr) * 256 + lk;
    const bf16_t* bpv = BTv + (size_t)(n0 + lr) * 256 + lk;

    f32x4 acck[2][4], accv[2][4];
#pragma unroll
    for (int m = 0; m < 2; ++m)
#pragma unroll
        for (int j = 0; j < 4; ++j) { acck[m][j] = (f32x4)0.f; accv[m][j] = (f32x4)0.f; }

#pragma unroll 2
    for (int k0 = 0; k0 < 256; k0 += 32) {
        bf16x8 a0 = *(const bf16x8*)(ap0 + k0);
        bf16x8 a1 = *(const bf16x8*)(ap1 + k0);
#pragma unroll
        for (int j = 0; j < 4; ++j) {
            bf16x8 bk = *(const bf16x8*)(bpk + (size_t)j * 16 * 256 + k0);
            bf16x8 bv = *(const bf16x8*)(bpv + (size_t)j * 16 * 256 + k0);
            // swapped operands: output is C^T fragment -> lane holds
            // C[m0+m*16+lr][n0+j*16+4*lg .. +3] (4 consecutive cols)
            acck[0][j] = __builtin_amdgcn_mfma_f32_16x16x32_bf16(bk, a0, acck[0][j], 0, 0, 0);
            acck[1][j] = __builtin_amdgcn_mfma_f32_16x16x32_bf16(bk, a1, acck[1][j], 0, 0, 0);
            accv[0][j] = __builtin_amdgcn_mfma_f32_16x16x32_bf16(bv, a0, accv[0][j], 0, 0, 0);
            accv[1][j] = __builtin_amdgcn_mfma_f32_16x16x32_bf16(bv, a1, accv[1][j], 0, 0, 0);
        }
    }

    const int lg4 = (lane >> 4) * 4;
#pragma unroll
    for (int m = 0; m < 2; ++m) {
        const size_t rowoff = (size_t)(m0 + m * 16 + lr) * 256;
#pragma unroll
        for (int j = 0; j < 4; ++j) {
            const int col = n0 + j * 16 + lg4;
            bf16x4 ok, ov;
#pragma unroll
            for (int r = 0; r < 4; ++r) {
                ok[r] = (bf16_t)acck[m][j][r];
                ov[r] = (bf16_t)accv[m][j][r];
            }
            *(bf16x4*)(Ck + rowoff + col) = ok;
            *(bf16x4*)(Cv + rowoff + col) = ov;
        }
    }
}

// ---------------------------------------------------------------------------
// qc partials: qcpart[kc][b][n] = sum_{k in chunk kc} ctx[b][k]*Wq[260+k][n]
// grid (64, 4). ctx element is wave-uniform -> scalar loads.
// ---------------------------------------------------------------------------
__global__ __launch_bounds__(256) void qc_kernel(
    const float* __restrict__ ctx, const float* __restrict__ Wq,
    float* __restrict__ qcpart)
{
    const int b = blockIdx.x;
    const int kc = blockIdx.y;
    const int tid = threadIdx.x;
    const float* c = ctx + (size_t)b * CTX_ + kc * 256;
    const float* w = Wq + (size_t)(260 + kc * 256) * EMB_ + tid;
    float acc = 0.f;
#pragma unroll 8
    for (int kk = 0; kk < 256; ++kk)
        acc = fmaf(c[kk], w[(size_t)kk * EMB_], acc);
    qcpart[((size_t)kc * 64 + b) * EMB_ + tid] = acc;
}

// ---------------------------------------------------------------------------
// q[m][n] += attr[m][0..3] . Wq[256..259][n]  +  sum_kc qcpart[kc][b][n]
// ---------------------------------------------------------------------------
__global__ __launch_bounds__(256) void qfix_kernel(
    const float* __restrict__ attr, const float* __restrict__ Wq,
    const float* __restrict__ qcpart, float* __restrict__ q)
{
    const int idx = blockIdx.x * 256 + threadIdx.x;
    const int n = idx & 255;
    const int m = idx >> 8;
    const int b = m / P_;
    float a0 = attr[(size_t)m * 4 + 0];
    float a1 = attr[(size_t)m * 4 + 1];
    float a2 = attr[(size_t)m * 4 + 2];
    float a3 = attr[(size_t)m * 4 + 3];
    float add = 0.f;
#pragma unroll
    for (int kc = 0; kc < 4; ++kc)
        add += qcpart[((size_t)kc * 64 + b) * EMB_ + n];
    add = fmaf(a0, Wq[(size_t)256 * EMB_ + n], add);
    add = fmaf(a1, Wq[(size_t)257 * EMB_ + n], add);
    add = fmaf(a2, Wq[(size_t)258 * EMB_ + n], add);
    add = fmaf(a3, Wq[(size_t)259 * EMB_ + n], add);
    q[idx] += add;
}

// ---------------------------------------------------------------------------
// MFMA flash attention. Grid 448 x 1024 (16 waves = 16 heads per (b,mtile)).
// defer-max (THR=8) keeps the common path free of cross-lane ops;
// two interleaved accumulation states (even/odd chunks) double ILP.
// XCD-bijective block mapping keeps one b's blocks on one XCD L2.
// ---------------------------------------------------------------------------
struct AttnState { float m, l; f32x4 acc; };

template<bool TAIL>
__device__ __forceinline__ void attn_chunk(
    int n0, const bf16_t* __restrict__ kb, const bf16_t* __restrict__ vb,
    const float* __restrict__ maskrow, bf16x8 qfrag, int lr, int lg,
    AttnState& st)
{
    // K A-frag: row n = n0+lr, k(d) = 8*(lg&1)+i ; zero for lg>=2
    int nk = n0 + lr;
    if (TAIL) nk = (nk < N_) ? nk : (N_ - 1);
    bf16x8 ak = *(const bf16x8*)(kb + (size_t)nk * 256 + (lg & 1) * 8);
    if (lg >= 2) ak = (bf16x8)(bf16_t)0.0f;

    f32x4 sc = __builtin_amdgcn_mfma_f32_16x16x32_bf16(ak, qfrag, (f32x4)0.f, 0, 0, 0);

    // scores + mask (lane's 4 keys n = n0+4*lg+r, query p = lr)
    int nm = n0 + 4 * lg;
    if (TAIL) nm = (nm < 996) ? nm : 996;
    float4 mk = *(const float4*)&maskrow[nm];
    float s0 = fmaf(sc[0], 0.25f, mk.x);
    float s1 = fmaf(sc[1], 0.25f, mk.y);
    float s2 = fmaf(sc[2], 0.25f, mk.z);
    float s3 = fmaf(sc[3], 0.25f, mk.w);
    if (TAIL) {
        if (n0 + 4 * lg + 0 >= N_) s0 = -3.0e38f;
        if (n0 + 4 * lg + 1 >= N_) s1 = -3.0e38f;
        if (n0 + 4 * lg + 2 >= N_) s2 = -3.0e38f;
        if (n0 + 4 * lg + 3 >= N_) s3 = -3.0e38f;
    }

    // defer-max: common path is per-lane only (no cross-lane ops)
    float tmax = fmaxf(fmaxf(s0, s1), fmaxf(s2, s3));
    if (__any(tmax > st.m + 8.0f)) {        // rare (~once per state)
        float rmax = fmaxf(tmax, __shfl_xor(tmax, 16));
        rmax = fmaxf(rmax, __shfl_xor(rmax, 32));
        float mn = fmaxf(st.m, rmax);
        asm volatile("s_nop 7\n\ts_nop 3"); // MFMA->VALU read of st.acc
        float f = EXP2F((st.m - mn) * L2E); // first time: exp2(-inf)=0
        st.l *= f;
        st.acc *= f;
        st.m = mn;
    }
    float w0 = EXP2F((s0 - st.m) * L2E);    // bounded by e^8
    float w1 = EXP2F((s1 - st.m) * L2E);
    float w2 = EXP2F((s2 - st.m) * L2E);
    float w3 = EXP2F((s3 - st.m) * L2E);
    st.l += (w0 + w1) + (w2 + w3);
    bf16x4 pb;
    pb[0] = (bf16_t)w0; pb[1] = (bf16_t)w1; pb[2] = (bf16_t)w2; pb[3] = (bf16_t)w3;

    // V^T A-frag: row d = lr, k(n) = 4*lg+i  -> V[n0+4lg+i][d=lr]
    bf16x4 av;
#pragma unroll
    for (int i = 0; i < 4; ++i) {
        int nn = n0 + 4 * lg + i;
        if (TAIL) nn = (nn < N_) ? nn : (N_ - 1);   // w=0 kills contribution
        av[i] = vb[(size_t)nn * 256 + lr];
    }
    pv_mfma16(av, pb, st.acc);
}

__global__ __launch_bounds__(1024) void attn_mfma(
    const float* __restrict__ q, const bf16_t* __restrict__ k,
    const bf16_t* __restrict__ v, const float* __restrict__ mask,
    bf16_t* __restrict__ abuf)
{
    // XCD-bijective block mapping: 448 = 8 xcd * 56 slots; 56 = 8 b-groups * 7
    const int x = blockIdx.x;
    const int xcd = x & 7;
    const int slot = x >> 3;                 // 0..55
    const int b = xcd + 8 * (slot / 7);
    const int mtile = slot % 7;
    const int h = threadIdx.x >> 6;          // wave = head
    const int lane = threadIdx.x & 63;
    const int p0 = mtile * 16;
    const int lr = lane & 15;
    const int lg = lane >> 4;

    // Q B-frag (x32): col p = lr, k(d) = 8*lg+i ; zero for lg>=2
    const int pq = (p0 + lr < P_) ? (p0 + lr) : (P_ - 1);
    bf16x8 qfrag = (bf16x8)(bf16_t)0.0f;
    if (lg < 2) {
        const float* qp = q + ((size_t)b * P_ + pq) * 256 + h * 16 + lg * 8;
        float4 q0 = *(const float4*)qp;
        float4 q1 = *(const float4*)(qp + 4);
        qfrag[0] = (bf16_t)q0.x; qfrag[1] = (bf16_t)q0.y;
        qfrag[2] = (bf16_t)q0.z; qfrag[3] = (bf16_t)q0.w;
        qfrag[4] = (bf16_t)q1.x; qfrag[5] = (bf16_t)q1.y;
        qfrag[6] = (bf16_t)q1.z; qfrag[7] = (bf16_t)q1.w;
    }

    const bf16_t* kb = k + ((size_t)b * N_) * 256 + h * 16;
    const bf16_t* vb = v + ((size_t)b * N_) * 256 + h * 16;
    const float* maskrow = mask + ((size_t)b * P_ + pq) * N_;

    AttnState stA, stB;
    stA.m = -INFINITY; stA.l = 0.f; stA.acc = (f32x4)0.f;
    stB.m = -INFINITY; stB.l = 0.f; stB.acc = (f32x4)0.f;

    // 63 chunks: 30 pairs + chunks 960(A), 976(B), 992(A,tail)
    for (int n0 = 0; n0 < 960; n0 += 32) {
        attn_chunk<false>(n0,      kb, vb, maskrow, qfrag, lr, lg, stA);
        attn_chunk<false>(n0 + 16, kb, vb, maskrow, qfrag, lr, lg, stB);
    }
    attn_chunk<false>(960, kb, vb, maskrow, qfrag, lr, lg, stA);
    attn_chunk<false>(976, kb, vb, maskrow, qfrag, lr, lg, stB);
    attn_chunk<true>(992, kb, vb, maskrow, qfrag, lr, lg, stA);

    // merge the two states (flash combine)
    asm volatile("s_nop 7\n\ts_nop 3");       // MFMA->VALU read of accs
    float mn = fmaxf(stA.m, stB.m);
    float fA = EXP2F((stA.m - mn) * L2E);
    float fB = EXP2F((stB.m - mn) * L2E);
    float l = stA.l * fA + stB.l * fB;
    f32x4 acc = stA.acc * fA + stB.acc * fB;

    // row sum of l across the 4 lanes sharing lr
    float L = l + __shfl_xor(l, 16);
    L += __shfl_xor(L, 32);

    if (p0 + lr < P_) {
        float inv = 1.0f / L;
        bf16x4 o;
        o[0] = (bf16_t)(acc[0] * inv);
        o[1] = (bf16_t)(acc[1] * inv);
        o[2] = (bf16_t)(acc[2] * inv);
        o[3] = (bf16_t)(acc[3] * inv);
        // out^T: lane holds out[p=lr][d=4*lg+r]
        *(bf16x4*)(abuf + ((size_t)b * P_ + p0 + lr) * 256 + h * 16 + 4 * lg) = o;
    }
}

// ---------------------------------------------------------------------------
// Pointer logits via MFMA. Grid 1024 blocks x 256 threads (4 waves).
// Block = one (b, 64-key n-group); all 4 waves share the B-frags (L1),
// each wave computes 2 mtiles (8 slots, mtile 7 discarded at epilogue).
// XCD-bijective: the 16 ngrp-blocks of one b land on one XCD.
// ---------------------------------------------------------------------------
__global__ __launch_bounds__(256) void logits_mfma(
    const bf16_t* __restrict__ mh, const bf16_t* __restrict__ nodes,
    const float* __restrict__ mask, float* __restrict__ out)
{
    // 1024 = 8 xcd * 128 slots; 128 = 8 b-groups * 16 ngrps
    const int x = blockIdx.x;
    const int xcd = x & 7;
    const int slot = x >> 3;                  // 0..127
    const int b = xcd + 8 * (slot >> 4);
    const int ngrp = slot & 15;
    const int wave = threadIdx.x >> 6;
    const int lane = threadIdx.x & 63;
    const int n0 = ngrp * 64;
    const int lr = lane & 15;
    const int lk = (lane >> 4) * 8;

    const bf16_t* bbase = nodes + (size_t)b * N_ * 256;
    int nrow[4];
#pragma unroll
    for (int j = 0; j < 4; ++j) {
        int n = n0 + j * 16 + lr;
        nrow[j] = (n < N_) ? n : (N_ - 1);
    }

    // two mtiles per wave: mt = wave + 4*t (t=0,1); mt==7 discarded.
    // mh rows beyond P_ (up to 127) are safe: mhbuf overlay has slack.
    const bf16_t* ap0 = mh + ((size_t)(b * P_) + (wave + 0) * 16 + lr) * 256 + lk;
    const bf16_t* ap1 = mh + ((size_t)(b * P_) + (wave + 4) * 16 + lr) * 256 + lk;

    f32x4 acc0[4], acc1[4];
#pragma unroll
    for (int j = 0; j < 4; ++j) { acc0[j] = (f32x4)0.f; acc1[j] = (f32x4)0.f; }

#pragma unroll 2
    for (int k0 = 0; k0 < 256; k0 += 32) {
        bf16x8 a0 = *(const bf16x8*)(ap0 + k0);
        bf16x8 a1 = *(const bf16x8*)(ap1 + k0);
#pragma unroll
        for (int j = 0; j < 4; ++j) {
            bf16x8 bfr = *(const bf16x8*)(bbase + (size_t)nrow[j] * 256 + lk + k0);
            acc0[j] = __builtin_amdgcn_mfma_f32_16x16x32_bf16(a0, bfr, acc0[j], 0, 0, 0);
            acc1[j] = __builtin_amdgcn_mfma_f32_16x16x32_bf16(a1, bfr, acc1[j], 0, 0, 0);
        }
    }

#pragma unroll
    for (int t = 0; t < 2; ++t) {
        const int mt = wave + 4 * t;
        if (mt >= 7) continue;                 // wave-uniform
        const int prow = mt * 16 + (lane >> 4) * 4;
        f32x4* acc = t ? acc1 : acc0;
#pragma unroll
        for (int j = 0; j < 4; ++j) {
            const int n = n0 + j * 16 + lr;
            if (n >= N_) continue;
#pragma unroll
            for (int r = 0; r < 4; ++r) {
                const int p = prow + r;
                if (p >= P_) continue;
                float xv = acc[j][r] * (1.0f / 16.0f);
                float e = EXP2F(xv * (2.0f * L2E));
                float tt = 1.0f - 2.0f / (e + 1.0f);
                size_t oidx = ((size_t)(b * P_ + p)) * N_ + n;
                out[oidx] = 10.0f * tt + mask[oidx];
            }
        }
    }
}

// ---------------------------------------------------------------------------
// In-place row softmax over N=1000. One block per row, 256 threads.
// ---------------------------------------------------------------------------
__global__ __launch_bounds__(256) void softmax_kernel(float* __restrict__ io)
{
    const size_t row = blockIdx.x;
    float* r = &io[row * N_];
    const int tid = threadIdx.x;
    const int wave = tid >> 6, lane = tid & 63;

    float vals[4];
    float mx = -INFINITY;
#pragma unroll
    for (int j = 0; j < 4; ++j) {
        int n = tid + j * 256;
        vals[j] = (n < N_) ? r[n] : -INFINITY;
        mx = fmaxf(mx, vals[j]);
    }
#pragma unroll
    for (int off = 32; off > 0; off >>= 1) mx = fmaxf(mx, __shfl_down(mx, off));
    __shared__ float redm[4];
    if (lane == 0) redm[wave] = mx;
    __syncthreads();
    mx = fmaxf(fmaxf(redm[0], redm[1]), fmaxf(redm[2], redm[3]));

    float sum = 0.f;
#pragma unroll
    for (int j = 0; j < 4; ++j) {
        float w = EXP2F((vals[j] - mx) * L2E);
        vals[j] = w;
        sum += w;
    }
#pragma unroll
    for (int off = 32; off > 0; off >>= 1) sum += __shfl_down(sum, off);
    __shared__ float reds[4];
    if (lane == 0) reds[wave] = sum;
    __syncthreads();
    sum = reds[0] + reds[1] + reds[2] + reds[3];

    float inv = 1.0f / sum;
#pragma unroll
    for (int j = 0; j < 4; ++j) {
        int n = tid + j * 256;
        if (n < N_) r[n] = vals[j] * inv;
    }
}

// ---------------------------------------------------------------------------
extern "C" void kernel_launch(void* const* d_in, const int* in_sizes, int n_in,
                              void* d_out, int out_size, void* d_ws, size_t ws_size,
                              hipStream_t stream)
{
    const float* lastnode = (const float*)d_in[0];   // [B,P,256]
    const float* attr     = (const float*)d_in[1];   // [B,P,4]
    const float* ctx      = (const float*)d_in[2];   // [B,1024]
    const float* mask     = (const float*)d_in[3];   // [B,P,N]
    const float* nodes    = (const float*)d_in[4];   // [B,N,256]
    const float* Wq       = (const float*)d_in[5];   // [1284,256]
    const float* Wk       = (const float*)d_in[6];   // [256,256]
    const float* Wv       = (const float*)d_in[7];   // [256,256]
    const float* Wcomb    = (const float*)d_in[8];   // [256,256]
    const float* bcomb    = (const float*)d_in[9];   // [256]
    float* out = (float*)d_out;

    // Workspace layout (offsets in floats). Total 28,049,408 f = 112.2 MB.
    float* ws = (float*)d_ws;
    bf16_t* kbuf   = (bf16_t*)(ws);                   // 16,384,000 bf16
    bf16_t* vbuf   = (bf16_t*)(ws + 8192000);         // 16,384,000 bf16
    float*  qbuf   = ws + 16384000;                   // 1,638,400 f
    bf16_t* nbf    = (bf16_t*)(ws + 18022400);        // 16,384,000 bf16
    bf16_t* WkT    = (bf16_t*)(ws + 26214400);        // 65,536 bf16
    bf16_t* WvT    = (bf16_t*)(ws + 26247168);        // 65,536 bf16
    bf16_t* WcombT = (bf16_t*)(ws + 26279936);        // 65,536 bf16
    bf16_t* WqmT   = (bf16_t*)(ws + 26312704);        // 65,536 bf16
    float*  qcpart = ws + 26345472;                   // 65,536 f (4x64x256)
    bf16_t* abuf   = (bf16_t*)(ws + 26411008);        // 1,638,400 bf16
    bf16_t* lnbf   = (bf16_t*)(ws + 27230208);        // 1,638,400 bf16
    // Overlay: mhbuf reuses kbuf (K dead after attn_mfma); logits reads rows
    // up to b*100+127 -> slack is inside kbuf's 16.4M elements.
    bf16_t* mhbuf = kbuf;

    // 1) nodes & lastnode -> bf16
    cvt_bf16_kernel<<<16000, 256, 0, stream>>>(nodes, nbf, 4096000);
    cvt_bf16_kernel<<<1600, 256, 0, stream>>>(lastnode, lnbf, 409600);

    // 2) weight transposes -> bf16 (Wk, Wv, Wcomb, Wq[0:256))
    wtrans_kernel<<<dim3(8, 8, 4), 256, 0, stream>>>(
        Wk, Wv, Wcomb, Wq, WkT, WvT, WcombT, WqmT);

    // 3) q pipeline: main term MFMA (f32 out) + ctx partials + fixup
    qc_kernel<<<dim3(64, 4), 256, 0, stream>>>(ctx, Wq, qcpart);
    mfma_gemm<false, false><<<400, 256, 0, stream>>>(lnbf, WqmT, nullptr, qbuf);
    qfix_kernel<<<6400, 256, 0, stream>>>(attr, Wq, qcpart, qbuf);

    // 4) fused k+v projection (MFMA v2, bf16 out, coalesced stores)
    mfma_gemm_kv<<<2000, 256, 0, stream>>>(nbf, WkT, WvT, kbuf, vbuf);

    // 5) fused MFMA flash attention -> abuf (bf16)
    attn_mfma<<<448, 1024, 0, stream>>>(qbuf, kbuf, vbuf, mask, abuf);

    // 6) combine projection (MFMA, bias, bf16 out into mhbuf)
    mfma_gemm<true, true><<<400, 256, 0, stream>>>(abuf, WcombT, bcomb, mhbuf);

    // 7) pointer logits (MFMA) + softmax
    logits_mfma<<<1024, 256, 0, stream>>>(mhbuf, nbf, mask, out);
    softmax_kernel<<<B_ * P_, 256, 0, stream>>>(out);
}